// Round 1
// baseline (5786.468 us; speedup 1.0000x reference)
//
#include <hip/hip_runtime.h>
#include <hip/hip_bf16.h>
#include <math.h>

#define L 4096
#define ECH 128
#define BCH 2
#define NHEAD 4
#define FUSEDC 257

// ---------------- transpose (B,128,4096) -> (B,4096,128) ----------------
__global__ void transpose_kernel(const float* __restrict__ in, float* __restrict__ out) {
  __shared__ float t[32][33];
  int b = blockIdx.z;
  int bx = blockIdx.x * 32;   // along 4096 (pixels)
  int by = blockIdx.y * 32;   // along 128 (channels)
  int tx = threadIdx.x & 31, ty = threadIdx.x >> 5; // 8 rows of 32
  const float* ip = in + (size_t)b * ECH * L;
  float* op = out + (size_t)b * L * ECH;
#pragma unroll
  for (int r = ty; r < 32; r += 8)
    t[r][tx] = ip[(size_t)(by + r) * L + bx + tx];
  __syncthreads();
#pragma unroll
  for (int r = ty; r < 32; r += 8)
    op[(size_t)(bx + r) * ECH + by + tx] = t[tx][r];
}

// ---------------- fused QKV projections (6 GEMV per pixel) ----------------
__global__ void qkv_kernel(const float* __restrict__ sfT, const float* __restrict__ tfT,
                           const float* __restrict__ wS, const float* __restrict__ bS,
                           const float* __restrict__ wT, const float* __restrict__ bT,
                           float* __restrict__ qs, float* __restrict__ ks, float* __restrict__ vs,
                           float* __restrict__ qt, float* __restrict__ kt, float* __restrict__ vt) {
  __shared__ __align__(16) float xs[128];
  __shared__ __align__(16) float xt[128];
  int bp = blockIdx.x; int c = threadIdx.x;
  size_t row = (size_t)bp * 128;
  xs[c] = sfT[row + c]; xt[c] = tfT[row + c];
  __syncthreads();
  float aq = 0, ak = 0, av = 0, aq2 = 0, ak2 = 0, av2 = 0;
  const float4* wSq = (const float4*)(wS + (size_t)c * 128);
  const float4* wSk = (const float4*)(wS + (size_t)(128 + c) * 128);
  const float4* wSv = (const float4*)(wS + (size_t)(256 + c) * 128);
  const float4* wTq = (const float4*)(wT + (size_t)c * 128);
  const float4* wTk = (const float4*)(wT + (size_t)(128 + c) * 128);
  const float4* wTv = (const float4*)(wT + (size_t)(256 + c) * 128);
  const float4* xs4 = (const float4*)xs;
  const float4* xt4 = (const float4*)xt;
#pragma unroll 4
  for (int e = 0; e < 32; ++e) {
    float4 a = xs4[e], bb = xt4[e];
    float4 w;
    w = wSq[e]; aq  += a.x * w.x + a.y * w.y + a.z * w.z + a.w * w.w;
    w = wSk[e]; ak  += bb.x * w.x + bb.y * w.y + bb.z * w.z + bb.w * w.w;
    w = wSv[e]; av  += bb.x * w.x + bb.y * w.y + bb.z * w.z + bb.w * w.w;
    w = wTq[e]; aq2 += bb.x * w.x + bb.y * w.y + bb.z * w.z + bb.w * w.w;
    w = wTk[e]; ak2 += a.x * w.x + a.y * w.y + a.z * w.z + a.w * w.w;
    w = wTv[e]; av2 += a.x * w.x + a.y * w.y + a.z * w.z + a.w * w.w;
  }
  qs[row + c] = aq + bS[c];
  ks[row + c] = ak + bS[128 + c];
  vs[row + c] = av + bS[256 + c];
  qt[row + c] = aq2 + bT[c];
  kt[row + c] = ak2 + bT[128 + c];
  vt[row + c] = av2 + bT[256 + c];
}

// ---------------- attention: one block per (q-row, head, batch) ----------------
__global__ void attn_kernel(const float* __restrict__ Q, const float* __restrict__ K,
                            const float* __restrict__ V, float* __restrict__ O) {
  __shared__ float sc[4096];
  __shared__ float red[256];
  __shared__ float qv[32];
  int qi = blockIdx.x, h = blockIdx.y, b = blockIdx.z;
  int tid = threadIdx.x;
  size_t base = (size_t)b * L * 128 + h * 32;
  if (tid < 32) qv[tid] = Q[base + (size_t)qi * 128 + tid];
  __syncthreads();
  const float scale = 0.17677669529663687f; // 1/sqrt(32)
  float lmax = -3e38f;
  for (int j = tid; j < L; j += 256) {
    const float4* kp = (const float4*)(K + base + (size_t)j * 128);
    float s = 0;
#pragma unroll
    for (int d0 = 0; d0 < 8; ++d0) {
      float4 kk = kp[d0];
      s += qv[4 * d0] * kk.x + qv[4 * d0 + 1] * kk.y + qv[4 * d0 + 2] * kk.z + qv[4 * d0 + 3] * kk.w;
    }
    s *= scale;
    sc[j] = s;
    lmax = fmaxf(lmax, s);
  }
  red[tid] = lmax; __syncthreads();
  for (int st = 128; st > 0; st >>= 1) { if (tid < st) red[tid] = fmaxf(red[tid], red[tid + st]); __syncthreads(); }
  float gmax = red[0];
  __syncthreads();
  float lsum = 0;
  for (int j = tid; j < L; j += 256) {
    float e = __expf(sc[j] - gmax);
    sc[j] = e; lsum += e;
  }
  red[tid] = lsum; __syncthreads();
  for (int st = 128; st > 0; st >>= 1) { if (tid < st) red[tid] += red[tid + st]; __syncthreads(); }
  float inv = 1.0f / red[0];
  __syncthreads();
  int d = tid & 31, chunk = tid >> 5; // 8 chunks x 512 keys
  const float* vp = V + base + d;
  float a0 = 0, a1 = 0, a2 = 0, a3 = 0;
  int j0 = chunk * 512;
  for (int j = j0; j < j0 + 512; j += 4) {
    a0 += sc[j]     * vp[(size_t)j * 128];
    a1 += sc[j + 1] * vp[(size_t)(j + 1) * 128];
    a2 += sc[j + 2] * vp[(size_t)(j + 2) * 128];
    a3 += sc[j + 3] * vp[(size_t)(j + 3) * 128];
  }
  red[(chunk << 5) + d] = a0 + a1 + a2 + a3;
  __syncthreads();
  if (tid < 32) {
    float t = 0;
#pragma unroll
    for (int cc = 0; cc < 8; ++cc) t += red[(cc << 5) + tid];
    O[base + (size_t)qi * 128 + tid] = t * inv;
  }
}

// ---------------- out-projection + write into fused (B,257,HW) ----------------
__global__ void outproj_kernel(const float* __restrict__ aos, const float* __restrict__ aot,
                               const float* __restrict__ w1, const float* __restrict__ b1,
                               const float* __restrict__ w2, const float* __restrict__ b2,
                               const float* __restrict__ gnn, float* __restrict__ fused) {
  __shared__ __align__(16) float a1[128];
  __shared__ __align__(16) float a2[128];
  int bp = blockIdx.x; int c = threadIdx.x;
  int b = bp >> 12, p = bp & 4095;
  size_t row = (size_t)bp * 128;
  a1[c] = aos[row + c]; a2[c] = aot[row + c];
  __syncthreads();
  const float4* w1r = (const float4*)(w1 + (size_t)c * 128);
  const float4* w2r = (const float4*)(w2 + (size_t)c * 128);
  const float4* a14 = (const float4*)a1;
  const float4* a24 = (const float4*)a2;
  float s1 = 0, s2 = 0;
#pragma unroll 4
  for (int e = 0; e < 32; ++e) {
    float4 x = a14[e], w = w1r[e];
    s1 += x.x * w.x + x.y * w.y + x.z * w.z + x.w * w.w;
    float4 y = a24[e], v = w2r[e];
    s2 += y.x * v.x + y.y * v.y + y.z * v.z + y.w * v.w;
  }
  size_t fbase = (size_t)b * FUSEDC * L;
  fused[fbase + (size_t)c * L + p] = s1 + b1[c];
  fused[fbase + (size_t)(128 + c) * L + p] = s2 + b2[c];
  if (c == 0) fused[fbase + (size_t)256 * L + p] = gnn[(size_t)b * L + p];
}

// ---------------- direct 3x3 conv, 4 co per thread ----------------
template <int CIN>
__global__ void conv3x3_kernel(const float* __restrict__ in, const float* __restrict__ w,
                               float* __restrict__ out) {
  int x = threadIdx.x & 63;
  int y = (blockIdx.x << 2) + (threadIdx.x >> 6);
  int cog = blockIdx.y; // 4 output channels per group
  int b = blockIdx.z;
  float acc0 = 0, acc1 = 0, acc2 = 0, acc3 = 0;
  const float* ip = in + (size_t)b * CIN * L;
  const float* wp = w + (size_t)cog * 4 * CIN * 9;
  for (int ci = 0; ci < CIN; ++ci) {
    const float* irow = ip + (size_t)ci * L;
    const float* wc = wp + (size_t)ci * 9;
#pragma unroll
    for (int ky = 0; ky < 3; ++ky) {
      int yy = y + ky - 1;
      if (yy < 0 || yy > 63) continue;
      const float* r = irow + yy * 64;
#pragma unroll
      for (int kx = 0; kx < 3; ++kx) {
        int xx = x + kx - 1;
        if (xx < 0 || xx > 63) continue;
        float v = r[xx];
        int t = ky * 3 + kx;
        acc0 += v * wc[t];
        acc1 += v * wc[CIN * 9 + t];
        acc2 += v * wc[2 * CIN * 9 + t];
        acc3 += v * wc[3 * CIN * 9 + t];
      }
    }
  }
  size_t ob = ((size_t)(b * 128 + (cog << 2)) * L) + y * 64 + x;
  out[ob] = acc0; out[ob + L] = acc1; out[ob + 2 * L] = acc2; out[ob + 3 * L] = acc3;
}

// ---------------- BN batch stats (training mode) ----------------
__global__ void bnstats_kernel(const float* __restrict__ x, float* __restrict__ mean, float* __restrict__ rstd) {
  __shared__ float rs[256], rq[256];
  int c = blockIdx.x, tid = threadIdx.x;
  float s = 0, q = 0;
  for (int i = tid; i < BCH * L; i += 256) {
    int b = i >> 12, p = i & 4095;
    float v = x[((size_t)(b * 128 + c)) * L + p];
    s += v; q += v * v;
  }
  rs[tid] = s; rq[tid] = q; __syncthreads();
  for (int st = 128; st > 0; st >>= 1) { if (tid < st) { rs[tid] += rs[tid + st]; rq[tid] += rq[tid + st]; } __syncthreads(); }
  if (tid == 0) {
    float m = rs[0] / (float)(BCH * L);
    float v = rq[0] / (float)(BCH * L) - m * m;
    mean[c] = m;
    rstd[c] = rsqrtf(v + 1e-5f);
  }
}

__global__ void bnapply_kernel(float* __restrict__ x, const float* __restrict__ mean, const float* __restrict__ rstd,
                               const float* __restrict__ g, const float* __restrict__ bb) {
  int i = blockIdx.x * 256 + threadIdx.x; // exactly B*128*4096 threads
  int c = (i >> 12) & 127;
  float v = x[i];
  float y = g[c] * (v - mean[c]) * rstd[c] + bb[c];
  x[i] = fmaxf(y, 0.0f);
}

// ---------------- fused 1x1 heads: pixel logit + MIL attention score ----------------
__global__ void head_kernel(const float* __restrict__ feat,
                            const float* __restrict__ w1, const float* __restrict__ b1,
                            const float* __restrict__ w2, const float* __restrict__ b2,
                            const float* __restrict__ wo, const float* __restrict__ bo,
                            float* __restrict__ score, float* __restrict__ plog) {
  __shared__ float f[128][64];
  __shared__ float r1[4][64], r2[4][64];
  int by = blockIdx.x; int b = by >> 6, y = by & 63;
  int tid = threadIdx.x;
  int x = tid & 63, g4 = tid >> 6;
  for (int c = g4; c < 128; c += 4)
    f[c][x] = feat[((size_t)(b * 128 + c)) * L + y * 64 + x];
  __syncthreads();
  int cb = g4 * 32;
  float a[32];
#pragma unroll
  for (int i = 0; i < 32; ++i) a[i] = b1[cb + i];
  for (int ci = 0; ci < 128; ++ci) {
    float fv = f[ci][x];
#pragma unroll
    for (int i = 0; i < 32; ++i) a[i] += w1[(size_t)(cb + i) * 128 + ci] * fv;
  }
  float sp = 0.0f;
#pragma unroll
  for (int i = 0; i < 32; ++i) sp += w2[cb + i] * fmaxf(a[i], 0.0f);
  float plp = 0.0f;
#pragma unroll
  for (int i = 0; i < 32; ++i) plp += wo[cb + i] * f[cb + i][x];
  r1[g4][x] = sp; r2[g4][x] = plp;
  __syncthreads();
  if (tid < 64) {
    int xx = tid;
    float s = r1[0][xx] + r1[1][xx] + r1[2][xx] + r1[3][xx] + b2[0];
    float pl = r2[0][xx] + r2[1][xx] + r2[2][xx] + r2[3][xx] + bo[0];
    score[(size_t)b * L + y * 64 + xx] = s;
    plog[(size_t)b * L + y * 64 + xx] = pl;
  }
}

// ---------------- masked softmax + attention maps + bag ----------------
__global__ void finalize_kernel(const float* __restrict__ score, const float* __restrict__ plog,
                                const int* __restrict__ zone, const int* __restrict__ cats,
                                float* __restrict__ maps, float* __restrict__ bag_ws) {
  __shared__ float sc[4096];
  __shared__ float red[256];
  __shared__ int ired[256];
  int b = blockIdx.x, tid = threadIdx.x;
  int cat = cats[b];
  float lmax = -3e38f; int lhas = 0;
  for (int p = tid; p < 4096; p += 256) {
    int z = zone[(size_t)b * 4096 + p];
    int m = (z == cat) && (z > 0);
    float s = m ? score[(size_t)b * 4096 + p] : -1e9f;
    sc[p] = s; lmax = fmaxf(lmax, s); lhas |= m;
  }
  red[tid] = lmax; ired[tid] = lhas; __syncthreads();
  for (int st = 128; st > 0; st >>= 1) {
    if (tid < st) { red[tid] = fmaxf(red[tid], red[tid + st]); ired[tid] |= ired[tid + st]; }
    __syncthreads();
  }
  float gmax = red[0]; int has = ired[0];
  __syncthreads();
  float lsum = 0;
  for (int p = tid; p < 4096; p += 256) {
    float e = __expf(sc[p] - gmax);
    sc[p] = e; lsum += e;
  }
  red[tid] = lsum; __syncthreads();
  for (int st = 128; st > 0; st >>= 1) { if (tid < st) red[tid] += red[tid + st]; __syncthreads(); }
  float inv = 1.0f / red[0];
  __syncthreads();
  float lbag = 0;
  for (int p = tid; p < 4096; p += 256) {
    float w = sc[p] * inv;
    maps[(size_t)b * 4096 + p] = has ? w : 0.0f;
    int z = zone[(size_t)b * 4096 + p];
    if ((z == cat) && (z > 0)) lbag += plog[(size_t)b * 4096 + p] * w;
  }
  red[tid] = lbag; __syncthreads();
  for (int st = 128; st > 0; st >>= 1) { if (tid < st) red[tid] += red[tid + st]; __syncthreads(); }
  if (tid == 0) bag_ws[b] = has ? red[0] : 0.0f;
}

__global__ void loss_kernel(const float* __restrict__ bag_ws, const float* __restrict__ labels,
                            float* __restrict__ out) {
  if (threadIdx.x == 0 && blockIdx.x == 0) {
    float t = 0;
    for (int b = 0; b < BCH; ++b) {
      float x = bag_ws[b];
      float sp = fmaxf(x, 0.0f) + log1pf(expf(-fabsf(x)));
      t += sp - x * labels[b];
    }
    out[0] = t / (float)BCH;
  }
}

extern "C" void kernel_launch(void* const* d_in, const int* in_sizes, int n_in,
                              void* d_out, int out_size, void* d_ws, size_t ws_size,
                              hipStream_t stream) {
  (void)in_sizes; (void)n_in; (void)out_size; (void)ws_size;
  const float* state = (const float*)d_in[0];
  const float* trig  = (const float*)d_in[1];
  const float* gnn   = (const float*)d_in[2];
  const int*   zone  = (const int*)d_in[3];
  const int*   cats  = (const int*)d_in[4];
  const float* labels = (const float*)d_in[5];
  const float* s2t_qkv_w = (const float*)d_in[6];
  const float* s2t_qkv_b = (const float*)d_in[7];
  const float* s2t_out_w = (const float*)d_in[8];
  const float* s2t_out_b = (const float*)d_in[9];
  const float* t2s_qkv_w = (const float*)d_in[10];
  const float* t2s_qkv_b = (const float*)d_in[11];
  const float* t2s_out_w = (const float*)d_in[12];
  const float* t2s_out_b = (const float*)d_in[13];
  const float* fconv1_w = (const float*)d_in[14];
  const float* fbn1_g = (const float*)d_in[15];
  const float* fbn1_b = (const float*)d_in[16];
  const float* fconv2_w = (const float*)d_in[17];
  const float* fbn2_g = (const float*)d_in[18];
  const float* fbn2_b = (const float*)d_in[19];
  const float* outc_w = (const float*)d_in[20];
  const float* outc_b = (const float*)d_in[21];
  const float* attn1_w = (const float*)d_in[22];
  const float* attn1_b = (const float*)d_in[23];
  const float* attn2_w = (const float*)d_in[24];
  const float* attn2_b = (const float*)d_in[25];

  float* ws = (float*)d_ws;
  const size_t NBP = (size_t)BCH * L * 128; // 1,048,576 floats
  size_t o = 0;
  float* sfT = ws + o; o += NBP;
  float* tfT = ws + o; o += NBP;
  float* qs = ws + o; o += NBP;
  float* ks = ws + o; o += NBP;
  float* vs = ws + o; o += NBP;
  float* qt = ws + o; o += NBP;
  float* kt = ws + o; o += NBP;
  float* vt = ws + o; o += NBP;
  float* aos = ws + o; o += NBP;
  float* aot = ws + o; o += NBP;
  float* fused = ws + o; o += (size_t)BCH * FUSEDC * L;
  float* c1 = ws + o; o += NBP;
  float* c2 = ws + o; o += NBP;
  float* stats = ws + o; o += 512;  // mean1, rstd1, mean2, rstd2
  float* score = ws + o; o += (size_t)BCH * L;
  float* plog = ws + o; o += (size_t)BCH * L;
  float* bag = ws + o; o += 2;

  transpose_kernel<<<dim3(128, 4, BCH), 256, 0, stream>>>(state, sfT);
  transpose_kernel<<<dim3(128, 4, BCH), 256, 0, stream>>>(trig, tfT);

  qkv_kernel<<<BCH * L, 128, 0, stream>>>(sfT, tfT, s2t_qkv_w, s2t_qkv_b, t2s_qkv_w, t2s_qkv_b,
                                          qs, ks, vs, qt, kt, vt);

  attn_kernel<<<dim3(L, NHEAD, BCH), 256, 0, stream>>>(qs, ks, vs, aos);
  attn_kernel<<<dim3(L, NHEAD, BCH), 256, 0, stream>>>(qt, kt, vt, aot);

  outproj_kernel<<<BCH * L, 128, 0, stream>>>(aos, aot, s2t_out_w, s2t_out_b, t2s_out_w, t2s_out_b,
                                              gnn, fused);

  conv3x3_kernel<257><<<dim3(16, 32, BCH), 256, 0, stream>>>(fused, fconv1_w, c1);
  bnstats_kernel<<<128, 256, 0, stream>>>(c1, stats, stats + 128);
  bnapply_kernel<<<4096, 256, 0, stream>>>(c1, stats, stats + 128, fbn1_g, fbn1_b);

  conv3x3_kernel<128><<<dim3(16, 32, BCH), 256, 0, stream>>>(c1, fconv2_w, c2);
  bnstats_kernel<<<128, 256, 0, stream>>>(c2, stats + 256, stats + 384);
  bnapply_kernel<<<4096, 256, 0, stream>>>(c2, stats + 256, stats + 384, fbn2_g, fbn2_b);

  head_kernel<<<BCH * 64, 256, 0, stream>>>(c2, attn1_w, attn1_b, attn2_w, attn2_b,
                                            outc_w, outc_b, score, plog);

  finalize_kernel<<<BCH, 256, 0, stream>>>(score, plog, zone, cats, (float*)d_out + 1, bag);
  loss_kernel<<<1, 64, 0, stream>>>(bag, labels, (float*)d_out);
}

// Round 2
// 1676.981 us; speedup vs baseline: 3.4505x; 3.4505x over previous
//
#include <hip/hip_runtime.h>
#include <hip/hip_bf16.h>
#include <math.h>

#define L 4096
#define ECH 128
#define BCH 2
#define NHEAD 4
#define FUSEDC 257

typedef __attribute__((ext_vector_type(8))) short bs8;
typedef __attribute__((ext_vector_type(4))) short bs4;
typedef __attribute__((ext_vector_type(4))) float fx4;

// round-to-nearest-even f32 -> bf16 bits (values are finite, no NaN handling needed)
static __device__ __forceinline__ short f2bfs(float x) {
  unsigned u = __float_as_uint(x);
  u += 0x7fffu + ((u >> 16) & 1u);
  return (short)(u >> 16);
}

// ---------------- transpose (B,128,4096) -> (B,4096,128) ----------------
__global__ void transpose_kernel(const float* __restrict__ in, float* __restrict__ out) {
  __shared__ float t[32][33];
  int b = blockIdx.z;
  int bx = blockIdx.x * 32;   // along 4096 (pixels)
  int by = blockIdx.y * 32;   // along 128 (channels)
  int tx = threadIdx.x & 31, ty = threadIdx.x >> 5; // 8 rows of 32
  const float* ip = in + (size_t)b * ECH * L;
  float* op = out + (size_t)b * L * ECH;
#pragma unroll
  for (int r = ty; r < 32; r += 8)
    t[r][tx] = ip[(size_t)(by + r) * L + bx + tx];
  __syncthreads();
#pragma unroll
  for (int r = ty; r < 32; r += 8)
    op[(size_t)(bx + r) * ECH + by + tx] = t[tx][r];
}

// ---------------- fused QKV projections -> bf16 Q (pre-scaled), K, V^T ----------------
__global__ void qkv_kernel(const float* __restrict__ sfT, const float* __restrict__ tfT,
                           const float* __restrict__ wS, const float* __restrict__ bS,
                           const float* __restrict__ wT, const float* __restrict__ bT,
                           short* __restrict__ qs, short* __restrict__ ks, short* __restrict__ vTs,
                           short* __restrict__ qt, short* __restrict__ kt, short* __restrict__ vTt) {
  __shared__ __align__(16) float xs[128];
  __shared__ __align__(16) float xt[128];
  int bp = blockIdx.x; int c = threadIdx.x;
  int b = bp >> 12, p = bp & 4095;
  size_t row = (size_t)bp * 128;
  xs[c] = sfT[row + c]; xt[c] = tfT[row + c];
  __syncthreads();
  float aq = 0, ak = 0, av = 0, aq2 = 0, ak2 = 0, av2 = 0;
  const float4* wSq = (const float4*)(wS + (size_t)c * 128);
  const float4* wSk = (const float4*)(wS + (size_t)(128 + c) * 128);
  const float4* wSv = (const float4*)(wS + (size_t)(256 + c) * 128);
  const float4* wTq = (const float4*)(wT + (size_t)c * 128);
  const float4* wTk = (const float4*)(wT + (size_t)(128 + c) * 128);
  const float4* wTv = (const float4*)(wT + (size_t)(256 + c) * 128);
  const float4* xs4 = (const float4*)xs;
  const float4* xt4 = (const float4*)xt;
#pragma unroll 4
  for (int e = 0; e < 32; ++e) {
    float4 a = xs4[e], bb = xt4[e];
    float4 w;
    w = wSq[e]; aq  += a.x * w.x + a.y * w.y + a.z * w.z + a.w * w.w;
    w = wSk[e]; ak  += bb.x * w.x + bb.y * w.y + bb.z * w.z + bb.w * w.w;
    w = wSv[e]; av  += bb.x * w.x + bb.y * w.y + bb.z * w.z + bb.w * w.w;
    w = wTq[e]; aq2 += bb.x * w.x + bb.y * w.y + bb.z * w.z + bb.w * w.w;
    w = wTk[e]; ak2 += a.x * w.x + a.y * w.y + a.z * w.z + a.w * w.w;
    w = wTv[e]; av2 += a.x * w.x + a.y * w.y + a.z * w.z + a.w * w.w;
  }
  const float SC = 0.17677669529663687f; // 1/sqrt(32) baked into Q
  int hh = c >> 5, dd = c & 31;
  size_t vt_idx = ((size_t)(b * NHEAD + hh) * 32 + dd) * (size_t)L + p;
  qs[row + c] = f2bfs((aq + bS[c]) * SC);
  ks[row + c] = f2bfs(ak + bS[128 + c]);
  vTs[vt_idx] = f2bfs(av + bS[256 + c]);
  qt[row + c] = f2bfs((aq2 + bT[c]) * SC);
  kt[row + c] = f2bfs(ak2 + bT[128 + c]);
  vTt[vt_idx] = f2bfs(av2 + bT[256 + c]);
}

// ---------------- bf16 MFMA flash attention ----------------
// grid (64 qtile-groups, NHEAD, BCH), 256 threads = 4 independent waves, 16 q-rows/wave.
// Swapped QK^T: S^T tile = MFMA(A=K_tile16x32, B=Q^T) -> C/D col(lane&15)=q, row=key.
// P stays in C/D regs and feeds PV A-operand with key mapping g(u,j)=u*4+(j&3)+16*(j>>2);
// V^T is loaded with the same mapping, so the hardware k-permutation cancels.
__global__ void __launch_bounds__(256)
flash_attn_kernel(const short* __restrict__ Q, const short* __restrict__ K,
                  const short* __restrict__ VT, float* __restrict__ O) {
  int tid = threadIdx.x;
  int wid = tid >> 6, lane = tid & 63;
  int u = lane >> 4, r = lane & 15;
  int h = blockIdx.y, b = blockIdx.z;
  int qt = (blockIdx.x << 2) + wid;
  bs8 qf = *(const bs8*)(Q + ((size_t)(b * L + (qt << 4) + r) * 128 + h * 32 + u * 8));
  const short* Kb = K + (size_t)b * L * 128 + h * 32 + u * 8;
  const short* Vb = VT + ((size_t)(b * NHEAD + h) * 32) * (size_t)L;
  const short* v0p = Vb + (size_t)r * L + (u << 2);
  const short* v1p = Vb + (size_t)(16 + r) * L + (u << 2);
  fx4 o0 = {0.f, 0.f, 0.f, 0.f}, o1 = {0.f, 0.f, 0.f, 0.f};
  float m_run = -3.0e38f, l_run = 0.0f;
  for (int k0 = 0; k0 < L; k0 += 32) {
    bs8 a0 = *(const bs8*)(Kb + (size_t)(k0 + r) * 128);
    bs8 a1 = *(const bs8*)(Kb + (size_t)(k0 + 16 + r) * 128);
    fx4 zz = {0.f, 0.f, 0.f, 0.f};
    fx4 s0 = __builtin_amdgcn_mfma_f32_16x16x32_bf16(a0, qf, zz, 0, 0, 0);
    fx4 s1 = __builtin_amdgcn_mfma_f32_16x16x32_bf16(a1, qf, zz, 0, 0, 0);
    bs4 w0lo = *(const bs4*)(v0p + k0);
    bs4 w0hi = *(const bs4*)(v0p + k0 + 16);
    bs4 w1lo = *(const bs4*)(v1p + k0);
    bs4 w1hi = *(const bs4*)(v1p + k0 + 16);
    bs8 vb0 = __builtin_shufflevector(w0lo, w0hi, 0, 1, 2, 3, 4, 5, 6, 7);
    bs8 vb1 = __builtin_shufflevector(w1lo, w1hi, 0, 1, 2, 3, 4, 5, 6, 7);
    // online softmax; scores for q = r live in this lane's 8 regs (keys u*4+i, 16+u*4+i)
    float mx = fmaxf(fmaxf(s0[0], s0[1]), fmaxf(s0[2], s0[3]));
    mx = fmaxf(mx, fmaxf(fmaxf(s1[0], s1[1]), fmaxf(s1[2], s1[3])));
    mx = fmaxf(mx, __shfl_xor(mx, 16));
    mx = fmaxf(mx, __shfl_xor(mx, 32));
    float m_new = fmaxf(m_run, mx);
    float fsc = __expf(m_run - m_new);
    fx4 p0, p1;
#pragma unroll
    for (int i = 0; i < 4; ++i) { p0[i] = __expf(s0[i] - m_new); p1[i] = __expf(s1[i] - m_new); }
    float ls = (p0[0] + p0[1]) + (p0[2] + p0[3]) + (p1[0] + p1[1]) + (p1[2] + p1[3]);
    ls += __shfl_xor(ls, 16);
    ls += __shfl_xor(ls, 32);
    l_run = l_run * fsc + ls;
    m_run = m_new;
    // O rows are q = u*4+reg -> fetch that q's rescale factor from lane (u*4+reg)
#pragma unroll
    for (int reg = 0; reg < 4; ++reg) {
      float fo = __shfl(fsc, (u << 2) + reg);
      o0[reg] *= fo; o1[reg] *= fo;
    }
    bs8 pa;
#pragma unroll
    for (int i = 0; i < 4; ++i) { pa[i] = f2bfs(p0[i]); pa[i + 4] = f2bfs(p1[i]); }
    o0 = __builtin_amdgcn_mfma_f32_16x16x32_bf16(pa, vb0, o0, 0, 0, 0);
    o1 = __builtin_amdgcn_mfma_f32_16x16x32_bf16(pa, vb1, o1, 0, 0, 0);
  }
#pragma unroll
  for (int reg = 0; reg < 4; ++reg) {
    float linv = 1.0f / __shfl(l_run, (u << 2) + reg);
    size_t ob = ((size_t)b * L + (qt << 4) + (u << 2) + reg) * 128 + h * 32;
    O[ob + r] = o0[reg] * linv;
    O[ob + 16 + r] = o1[reg] * linv;
  }
}

// ---------------- out-projection + write into fused (B,257,HW) ----------------
__global__ void outproj_kernel(const float* __restrict__ aos, const float* __restrict__ aot,
                               const float* __restrict__ w1, const float* __restrict__ b1,
                               const float* __restrict__ w2, const float* __restrict__ b2,
                               const float* __restrict__ gnn, float* __restrict__ fused) {
  __shared__ __align__(16) float a1[128];
  __shared__ __align__(16) float a2[128];
  int bp = blockIdx.x; int c = threadIdx.x;
  int b = bp >> 12, p = bp & 4095;
  size_t row = (size_t)bp * 128;
  a1[c] = aos[row + c]; a2[c] = aot[row + c];
  __syncthreads();
  const float4* w1r = (const float4*)(w1 + (size_t)c * 128);
  const float4* w2r = (const float4*)(w2 + (size_t)c * 128);
  const float4* a14 = (const float4*)a1;
  const float4* a24 = (const float4*)a2;
  float s1 = 0, s2 = 0;
#pragma unroll 4
  for (int e = 0; e < 32; ++e) {
    float4 x = a14[e], w = w1r[e];
    s1 += x.x * w.x + x.y * w.y + x.z * w.z + x.w * w.w;
    float4 y = a24[e], v = w2r[e];
    s2 += y.x * v.x + y.y * v.y + y.z * v.z + y.w * v.w;
  }
  size_t fbase = (size_t)b * FUSEDC * L;
  fused[fbase + (size_t)c * L + p] = s1 + b1[c];
  fused[fbase + (size_t)(128 + c) * L + p] = s2 + b2[c];
  if (c == 0) fused[fbase + (size_t)256 * L + p] = gnn[(size_t)b * L + p];
}

// ---------------- direct 3x3 conv, 4 co per thread ----------------
template <int CIN>
__global__ void conv3x3_kernel(const float* __restrict__ in, const float* __restrict__ w,
                               float* __restrict__ out) {
  int x = threadIdx.x & 63;
  int y = (blockIdx.x << 2) + (threadIdx.x >> 6);
  int cog = blockIdx.y; // 4 output channels per group
  int b = blockIdx.z;
  float acc0 = 0, acc1 = 0, acc2 = 0, acc3 = 0;
  const float* ip = in + (size_t)b * CIN * L;
  const float* wp = w + (size_t)cog * 4 * CIN * 9;
  for (int ci = 0; ci < CIN; ++ci) {
    const float* irow = ip + (size_t)ci * L;
    const float* wc = wp + (size_t)ci * 9;
#pragma unroll
    for (int ky = 0; ky < 3; ++ky) {
      int yy = y + ky - 1;
      if (yy < 0 || yy > 63) continue;
      const float* r = irow + yy * 64;
#pragma unroll
      for (int kx = 0; kx < 3; ++kx) {
        int xx = x + kx - 1;
        if (xx < 0 || xx > 63) continue;
        float v = r[xx];
        int t = ky * 3 + kx;
        acc0 += v * wc[t];
        acc1 += v * wc[CIN * 9 + t];
        acc2 += v * wc[2 * CIN * 9 + t];
        acc3 += v * wc[3 * CIN * 9 + t];
      }
    }
  }
  size_t ob = ((size_t)(b * 128 + (cog << 2)) * L) + y * 64 + x;
  out[ob] = acc0; out[ob + L] = acc1; out[ob + 2 * L] = acc2; out[ob + 3 * L] = acc3;
}

// ---------------- BN batch stats (training mode) ----------------
__global__ void bnstats_kernel(const float* __restrict__ x, float* __restrict__ mean, float* __restrict__ rstd) {
  __shared__ float rs[256], rq[256];
  int c = blockIdx.x, tid = threadIdx.x;
  float s = 0, q = 0;
  for (int i = tid; i < BCH * L; i += 256) {
    int b = i >> 12, p = i & 4095;
    float v = x[((size_t)(b * 128 + c)) * L + p];
    s += v; q += v * v;
  }
  rs[tid] = s; rq[tid] = q; __syncthreads();
  for (int st = 128; st > 0; st >>= 1) { if (tid < st) { rs[tid] += rs[tid + st]; rq[tid] += rq[tid + st]; } __syncthreads(); }
  if (tid == 0) {
    float m = rs[0] / (float)(BCH * L);
    float v = rq[0] / (float)(BCH * L) - m * m;
    mean[c] = m;
    rstd[c] = rsqrtf(v + 1e-5f);
  }
}

__global__ void bnapply_kernel(float* __restrict__ x, const float* __restrict__ mean, const float* __restrict__ rstd,
                               const float* __restrict__ g, const float* __restrict__ bb) {
  int i = blockIdx.x * 256 + threadIdx.x; // exactly B*128*4096 threads
  int c = (i >> 12) & 127;
  float v = x[i];
  float y = g[c] * (v - mean[c]) * rstd[c] + bb[c];
  x[i] = fmaxf(y, 0.0f);
}

// ---------------- fused 1x1 heads: pixel logit + MIL attention score ----------------
__global__ void head_kernel(const float* __restrict__ feat,
                            const float* __restrict__ w1, const float* __restrict__ b1,
                            const float* __restrict__ w2, const float* __restrict__ b2,
                            const float* __restrict__ wo, const float* __restrict__ bo,
                            float* __restrict__ score, float* __restrict__ plog) {
  __shared__ float f[128][64];
  __shared__ float r1[4][64], r2[4][64];
  int by = blockIdx.x; int b = by >> 6, y = by & 63;
  int tid = threadIdx.x;
  int x = tid & 63, g4 = tid >> 6;
  for (int c = g4; c < 128; c += 4)
    f[c][x] = feat[((size_t)(b * 128 + c)) * L + y * 64 + x];
  __syncthreads();
  int cb = g4 * 32;
  float a[32];
#pragma unroll
  for (int i = 0; i < 32; ++i) a[i] = b1[cb + i];
  for (int ci = 0; ci < 128; ++ci) {
    float fv = f[ci][x];
#pragma unroll
    for (int i = 0; i < 32; ++i) a[i] += w1[(size_t)(cb + i) * 128 + ci] * fv;
  }
  float sp = 0.0f;
#pragma unroll
  for (int i = 0; i < 32; ++i) sp += w2[cb + i] * fmaxf(a[i], 0.0f);
  float plp = 0.0f;
#pragma unroll
  for (int i = 0; i < 32; ++i) plp += wo[cb + i] * f[cb + i][x];
  r1[g4][x] = sp; r2[g4][x] = plp;
  __syncthreads();
  if (tid < 64) {
    int xx = tid;
    float s = r1[0][xx] + r1[1][xx] + r1[2][xx] + r1[3][xx] + b2[0];
    float pl = r2[0][xx] + r2[1][xx] + r2[2][xx] + r2[3][xx] + bo[0];
    score[(size_t)b * L + y * 64 + xx] = s;
    plog[(size_t)b * L + y * 64 + xx] = pl;
  }
}

// ---------------- masked softmax + attention maps + bag ----------------
__global__ void finalize_kernel(const float* __restrict__ score, const float* __restrict__ plog,
                                const int* __restrict__ zone, const int* __restrict__ cats,
                                float* __restrict__ maps, float* __restrict__ bag_ws) {
  __shared__ float sc[4096];
  __shared__ float red[256];
  __shared__ int ired[256];
  int b = blockIdx.x, tid = threadIdx.x;
  int cat = cats[b];
  float lmax = -3e38f; int lhas = 0;
  for (int p = tid; p < 4096; p += 256) {
    int z = zone[(size_t)b * 4096 + p];
    int m = (z == cat) && (z > 0);
    float s = m ? score[(size_t)b * 4096 + p] : -1e9f;
    sc[p] = s; lmax = fmaxf(lmax, s); lhas |= m;
  }
  red[tid] = lmax; ired[tid] = lhas; __syncthreads();
  for (int st = 128; st > 0; st >>= 1) {
    if (tid < st) { red[tid] = fmaxf(red[tid], red[tid + st]); ired[tid] |= ired[tid + st]; }
    __syncthreads();
  }
  float gmax = red[0]; int has = ired[0];
  __syncthreads();
  float lsum = 0;
  for (int p = tid; p < 4096; p += 256) {
    float e = __expf(sc[p] - gmax);
    sc[p] = e; lsum += e;
  }
  red[tid] = lsum; __syncthreads();
  for (int st = 128; st > 0; st >>= 1) { if (tid < st) red[tid] += red[tid + st]; __syncthreads(); }
  float inv = 1.0f / red[0];
  __syncthreads();
  float lbag = 0;
  for (int p = tid; p < 4096; p += 256) {
    float w = sc[p] * inv;
    maps[(size_t)b * 4096 + p] = has ? w : 0.0f;
    int z = zone[(size_t)b * 4096 + p];
    if ((z == cat) && (z > 0)) lbag += plog[(size_t)b * 4096 + p] * w;
  }
  red[tid] = lbag; __syncthreads();
  for (int st = 128; st > 0; st >>= 1) { if (tid < st) red[tid] += red[tid + st]; __syncthreads(); }
  if (tid == 0) bag_ws[b] = has ? red[0] : 0.0f;
}

__global__ void loss_kernel(const float* __restrict__ bag_ws, const float* __restrict__ labels,
                            float* __restrict__ out) {
  if (threadIdx.x == 0 && blockIdx.x == 0) {
    float t = 0;
    for (int b = 0; b < BCH; ++b) {
      float x = bag_ws[b];
      float sp = fmaxf(x, 0.0f) + log1pf(expf(-fabsf(x)));
      t += sp - x * labels[b];
    }
    out[0] = t / (float)BCH;
  }
}

extern "C" void kernel_launch(void* const* d_in, const int* in_sizes, int n_in,
                              void* d_out, int out_size, void* d_ws, size_t ws_size,
                              hipStream_t stream) {
  (void)in_sizes; (void)n_in; (void)out_size; (void)ws_size;
  const float* state = (const float*)d_in[0];
  const float* trig  = (const float*)d_in[1];
  const float* gnn   = (const float*)d_in[2];
  const int*   zone  = (const int*)d_in[3];
  const int*   cats  = (const int*)d_in[4];
  const float* labels = (const float*)d_in[5];
  const float* s2t_qkv_w = (const float*)d_in[6];
  const float* s2t_qkv_b = (const float*)d_in[7];
  const float* s2t_out_w = (const float*)d_in[8];
  const float* s2t_out_b = (const float*)d_in[9];
  const float* t2s_qkv_w = (const float*)d_in[10];
  const float* t2s_qkv_b = (const float*)d_in[11];
  const float* t2s_out_w = (const float*)d_in[12];
  const float* t2s_out_b = (const float*)d_in[13];
  const float* fconv1_w = (const float*)d_in[14];
  const float* fbn1_g = (const float*)d_in[15];
  const float* fbn1_b = (const float*)d_in[16];
  const float* fconv2_w = (const float*)d_in[17];
  const float* fbn2_g = (const float*)d_in[18];
  const float* fbn2_b = (const float*)d_in[19];
  const float* outc_w = (const float*)d_in[20];
  const float* outc_b = (const float*)d_in[21];
  const float* attn1_w = (const float*)d_in[22];
  const float* attn1_b = (const float*)d_in[23];
  const float* attn2_w = (const float*)d_in[24];
  const float* attn2_b = (const float*)d_in[25];

  float* ws = (float*)d_ws;
  const size_t NBP = (size_t)BCH * L * 128; // 1,048,576 floats
  size_t o = 0;
  float* sfT = ws + o; o += NBP;
  float* tfT = ws + o; o += NBP;
  float* aos = ws + o; o += NBP;
  float* aot = ws + o; o += NBP;
  float* fused = ws + o; o += (size_t)BCH * FUSEDC * L;
  float* c1 = ws + o; o += NBP;
  float* c2 = ws + o; o += NBP;
  float* stats = ws + o; o += 512;
  float* score = ws + o; o += (size_t)BCH * L;
  float* plog = ws + o; o += (size_t)BCH * L;
  float* bag = ws + o; o += 8;
  // bf16 (2-byte) buffers, each NBP elements -> NBP/2 float slots
  short* qsb = (short*)(ws + o); o += NBP / 2;
  short* ksb = (short*)(ws + o); o += NBP / 2;
  short* qtb = (short*)(ws + o); o += NBP / 2;
  short* ktb = (short*)(ws + o); o += NBP / 2;
  short* vTsb = (short*)(ws + o); o += NBP / 2;
  short* vTtb = (short*)(ws + o); o += NBP / 2;

  transpose_kernel<<<dim3(128, 4, BCH), 256, 0, stream>>>(state, sfT);
  transpose_kernel<<<dim3(128, 4, BCH), 256, 0, stream>>>(trig, tfT);

  qkv_kernel<<<BCH * L, 128, 0, stream>>>(sfT, tfT, s2t_qkv_w, s2t_qkv_b, t2s_qkv_w, t2s_qkv_b,
                                          qsb, ksb, vTsb, qtb, ktb, vTtb);

  flash_attn_kernel<<<dim3(64, NHEAD, BCH), 256, 0, stream>>>(qsb, ksb, vTsb, aos);
  flash_attn_kernel<<<dim3(64, NHEAD, BCH), 256, 0, stream>>>(qtb, ktb, vTtb, aot);

  outproj_kernel<<<BCH * L, 128, 0, stream>>>(aos, aot, s2t_out_w, s2t_out_b, t2s_out_w, t2s_out_b,
                                              gnn, fused);

  conv3x3_kernel<257><<<dim3(16, 32, BCH), 256, 0, stream>>>(fused, fconv1_w, c1);
  bnstats_kernel<<<128, 256, 0, stream>>>(c1, stats, stats + 128);
  bnapply_kernel<<<4096, 256, 0, stream>>>(c1, stats, stats + 128, fbn1_g, fbn1_b);

  conv3x3_kernel<128><<<dim3(16, 32, BCH), 256, 0, stream>>>(c1, fconv2_w, c2);
  bnstats_kernel<<<128, 256, 0, stream>>>(c2, stats + 256, stats + 384);
  bnapply_kernel<<<4096, 256, 0, stream>>>(c2, stats + 256, stats + 384, fbn2_g, fbn2_b);

  head_kernel<<<BCH * 64, 256, 0, stream>>>(c2, attn1_w, attn1_b, attn2_w, attn2_b,
                                            outc_w, outc_b, score, plog);

  finalize_kernel<<<BCH, 256, 0, stream>>>(score, plog, zone, cats, (float*)d_out + 1, bag);
  loss_kernel<<<1, 64, 0, stream>>>(bag, labels, (float*)d_out);
}

// Round 3
// 909.387 us; speedup vs baseline: 6.3630x; 1.8441x over previous
//
#include <hip/hip_runtime.h>
#include <hip/hip_bf16.h>
#include <math.h>

#define L 4096
#define ECH 128
#define BCH 2
#define NHEAD 4
#define FUSEDC 257

typedef __attribute__((ext_vector_type(8))) short bs8;
typedef __attribute__((ext_vector_type(4))) short bs4;
typedef __attribute__((ext_vector_type(4))) float fx4;

// round-to-nearest-even f32 -> bf16 bits
static __device__ __forceinline__ short f2bfs(float x) {
  unsigned u = __float_as_uint(x);
  u += 0x7fffu + ((u >> 16) & 1u);
  return (short)(u >> 16);
}

// ---------------- transpose (B,128,4096) f32 -> (B,4096,128) bf16 ----------------
__global__ void transpose_kernel(const float* __restrict__ in, short* __restrict__ out) {
  __shared__ float t[32][33];
  int b = blockIdx.z;
  int bx = blockIdx.x * 32;   // along 4096 (pixels)
  int by = blockIdx.y * 32;   // along 128 (channels)
  int tx = threadIdx.x & 31, ty = threadIdx.x >> 5;
  const float* ip = in + (size_t)b * ECH * L;
  short* op = out + (size_t)b * L * ECH;
#pragma unroll
  for (int r = ty; r < 32; r += 8)
    t[r][tx] = ip[(size_t)(by + r) * L + bx + tx];
  __syncthreads();
#pragma unroll
  for (int r = ty; r < 32; r += 8)
    op[(size_t)(bx + r) * ECH + by + tx] = f2bfs(t[tx][r]);
}

// ---------------- weight prep: f32 -> bf16 (Q rows pre-scaled by 1/sqrt(32)) -------
__global__ void prep_weights(const float* __restrict__ wS, const float* __restrict__ wT,
                             const float* __restrict__ woS, const float* __restrict__ woT,
                             short* __restrict__ wSb, short* __restrict__ wTb,
                             short* __restrict__ woSb, short* __restrict__ woTb) {
  int i = blockIdx.x * 256 + threadIdx.x;
  const float SC = 0.17677669529663687f;
  if (i < 49152) {
    float s = (i < 16384) ? SC : 1.0f;
    wSb[i] = f2bfs(wS[i] * s);
    wTb[i] = f2bfs(wT[i] * s);
  }
  if (i < 16384) {
    woSb[i] = f2bfs(woS[i]);
    woTb[i] = f2bfs(woT[i]);
  }
}

// ---------------- MFMA GEMM, orientation A=X,B=W^T -> pixel-major bf16 out ---------
// grid (128, 4): units Qs, Ks, Qt, Kt. 256 thr = 4 waves; wave: 16 pixels x 128 och.
__global__ void __launch_bounds__(256)
gemm_qk(const short* __restrict__ Xs, const short* __restrict__ Xt,
        const short* __restrict__ wSb, const short* __restrict__ wTb,
        const float* __restrict__ bS, const float* __restrict__ bT,
        short* __restrict__ qs, short* __restrict__ ks,
        short* __restrict__ qt, short* __restrict__ kt) {
  const float SC = 0.17677669529663687f;
  int unit = blockIdx.y;
  const short* X; const short* W; const float* bias; short* out; float scale;
  switch (unit) {
    case 0: X = Xs; W = wSb;         bias = bS;       out = qs; scale = SC;  break;
    case 1: X = Xt; W = wSb + 16384; bias = bS + 128; out = ks; scale = 1.f; break;
    case 2: X = Xt; W = wTb;         bias = bT;       out = qt; scale = SC;  break;
    default:X = Xs; W = wTb + 16384; bias = bT + 128; out = kt; scale = 1.f; break;
  }
  int tid = threadIdx.x;
  int wv = tid >> 6, lane = tid & 63, u = lane >> 4, r = lane & 15;
  int pblk = blockIdx.x * 64 + wv * 16;
  const short* xrow = X + (size_t)(pblk + r) * 128;
  fx4 acc[8] = {};
#pragma unroll
  for (int ksx = 0; ksx < 4; ++ksx) {
    int k0 = ksx * 32 + u * 8;
    bs8 a = *(const bs8*)(xrow + k0);
    const short* wp = W + (size_t)r * 128 + k0;
#pragma unroll
    for (int t = 0; t < 8; ++t) {
      bs8 wf = *(const bs8*)(wp + (size_t)t * 16 * 128);
      acc[t] = __builtin_amdgcn_mfma_f32_16x16x32_bf16(a, wf, acc[t], 0, 0, 0);
    }
  }
#pragma unroll
  for (int t = 0; t < 8; ++t) {
    float bv = bias[t * 16 + r] * scale;
#pragma unroll
    for (int reg = 0; reg < 4; ++reg) {
      int p = pblk + u * 4 + reg;
      out[(size_t)p * 128 + t * 16 + r] = f2bfs(acc[t][reg] + bv);
    }
  }
}

// ---------------- MFMA GEMM, orientation A=W,B=X^T -> channel-major out ------------
// ubase=0: units Vs, Vt (bf16 V^T layout). ubase=2: Os, Ot (f32 into fused + bias).
__global__ void __launch_bounds__(256)
gemm_vo(const short* __restrict__ Xs, const short* __restrict__ Xt,
        const short* __restrict__ aosb, const short* __restrict__ aotb,
        const short* __restrict__ wSb, const short* __restrict__ wTb,
        const short* __restrict__ woSb, const short* __restrict__ woTb,
        const float* __restrict__ bS, const float* __restrict__ bT,
        const float* __restrict__ boS, const float* __restrict__ boT,
        short* __restrict__ vTs, short* __restrict__ vTt,
        float* __restrict__ fused, int ubase) {
  int unit = ubase + blockIdx.y;
  const short* X; const short* W; const float* bias;
  switch (unit) {
    case 0: X = Xt;   W = wSb + 32768; bias = bS + 256; break;
    case 1: X = Xs;   W = wTb + 32768; bias = bT + 256; break;
    case 2: X = aosb; W = woSb;        bias = boS;      break;
    default:X = aotb; W = woTb;        bias = boT;      break;
  }
  int tid = threadIdx.x;
  int wv = tid >> 6, lane = tid & 63, u = lane >> 4, r = lane & 15;
  int pblk = blockIdx.x * 64 + wv * 16;
  const short* xrow = X + (size_t)(pblk + r) * 128;
  fx4 acc[8] = {};
#pragma unroll
  for (int ksx = 0; ksx < 4; ++ksx) {
    int k0 = ksx * 32 + u * 8;
    bs8 xb = *(const bs8*)(xrow + k0);
    const short* wp = W + (size_t)r * 128 + k0;
#pragma unroll
    for (int t = 0; t < 8; ++t) {
      bs8 wf = *(const bs8*)(wp + (size_t)t * 16 * 128);
      acc[t] = __builtin_amdgcn_mfma_f32_16x16x32_bf16(wf, xb, acc[t], 0, 0, 0);
    }
  }
  int p = pblk + r;
  int b = p >> 12, pl = p & 4095;
  if (unit < 2) {
    short* out = (unit == 0) ? vTs : vTt;
#pragma unroll
    for (int t = 0; t < 8; ++t) {
#pragma unroll
      for (int reg = 0; reg < 4; ++reg) {
        int och = t * 16 + u * 4 + reg;
        int h = och >> 5, d = och & 31;
        out[((size_t)(b * NHEAD + h) * 32 + d) * L + pl] = f2bfs(acc[t][reg] + bias[och]);
      }
    }
  } else {
    int ochbase = (unit == 2) ? 0 : 128;
#pragma unroll
    for (int t = 0; t < 8; ++t) {
#pragma unroll
      for (int reg = 0; reg < 4; ++reg) {
        int och = t * 16 + u * 4 + reg;
        fused[((size_t)b * FUSEDC + ochbase + och) * L + pl] = acc[t][reg] + bias[och];
      }
    }
  }
}

__global__ void copy_gnn(const float* __restrict__ gnn, float* __restrict__ fused) {
  int i = blockIdx.x * 256 + threadIdx.x; // 8192 total
  int b = i >> 12, p = i & 4095;
  fused[((size_t)b * FUSEDC + 256) * L + p] = gnn[i];
}

// ---------------- bf16 MFMA flash attention (O out in bf16) ----------------
__global__ void __launch_bounds__(256)
flash_attn_kernel(const short* __restrict__ Q, const short* __restrict__ K,
                  const short* __restrict__ VT, short* __restrict__ O) {
  int tid = threadIdx.x;
  int wid = tid >> 6, lane = tid & 63;
  int u = lane >> 4, r = lane & 15;
  int h = blockIdx.y, b = blockIdx.z;
  int qt = (blockIdx.x << 2) + wid;
  bs8 qf = *(const bs8*)(Q + ((size_t)(b * L + (qt << 4) + r) * 128 + h * 32 + u * 8));
  const short* Kb = K + (size_t)b * L * 128 + h * 32 + u * 8;
  const short* Vb = VT + ((size_t)(b * NHEAD + h) * 32) * (size_t)L;
  const short* v0p = Vb + (size_t)r * L + (u << 2);
  const short* v1p = Vb + (size_t)(16 + r) * L + (u << 2);
  fx4 o0 = {0.f, 0.f, 0.f, 0.f}, o1 = {0.f, 0.f, 0.f, 0.f};
  float m_run = -3.0e38f, l_run = 0.0f;
  for (int k0 = 0; k0 < L; k0 += 32) {
    bs8 a0 = *(const bs8*)(Kb + (size_t)(k0 + r) * 128);
    bs8 a1 = *(const bs8*)(Kb + (size_t)(k0 + 16 + r) * 128);
    fx4 zz = {0.f, 0.f, 0.f, 0.f};
    fx4 s0 = __builtin_amdgcn_mfma_f32_16x16x32_bf16(a0, qf, zz, 0, 0, 0);
    fx4 s1 = __builtin_amdgcn_mfma_f32_16x16x32_bf16(a1, qf, zz, 0, 0, 0);
    bs4 w0lo = *(const bs4*)(v0p + k0);
    bs4 w0hi = *(const bs4*)(v0p + k0 + 16);
    bs4 w1lo = *(const bs4*)(v1p + k0);
    bs4 w1hi = *(const bs4*)(v1p + k0 + 16);
    bs8 vb0 = __builtin_shufflevector(w0lo, w0hi, 0, 1, 2, 3, 4, 5, 6, 7);
    bs8 vb1 = __builtin_shufflevector(w1lo, w1hi, 0, 1, 2, 3, 4, 5, 6, 7);
    float mx = fmaxf(fmaxf(s0[0], s0[1]), fmaxf(s0[2], s0[3]));
    mx = fmaxf(mx, fmaxf(fmaxf(s1[0], s1[1]), fmaxf(s1[2], s1[3])));
    mx = fmaxf(mx, __shfl_xor(mx, 16));
    mx = fmaxf(mx, __shfl_xor(mx, 32));
    float m_new = fmaxf(m_run, mx);
    float fsc = __expf(m_run - m_new);
    fx4 p0, p1;
#pragma unroll
    for (int i = 0; i < 4; ++i) { p0[i] = __expf(s0[i] - m_new); p1[i] = __expf(s1[i] - m_new); }
    float ls = (p0[0] + p0[1]) + (p0[2] + p0[3]) + (p1[0] + p1[1]) + (p1[2] + p1[3]);
    ls += __shfl_xor(ls, 16);
    ls += __shfl_xor(ls, 32);
    l_run = l_run * fsc + ls;
    m_run = m_new;
#pragma unroll
    for (int reg = 0; reg < 4; ++reg) {
      float fo = __shfl(fsc, (u << 2) + reg);
      o0[reg] *= fo; o1[reg] *= fo;
    }
    bs8 pa;
#pragma unroll
    for (int i = 0; i < 4; ++i) { pa[i] = f2bfs(p0[i]); pa[i + 4] = f2bfs(p1[i]); }
    o0 = __builtin_amdgcn_mfma_f32_16x16x32_bf16(pa, vb0, o0, 0, 0, 0);
    o1 = __builtin_amdgcn_mfma_f32_16x16x32_bf16(pa, vb1, o1, 0, 0, 0);
  }
#pragma unroll
  for (int reg = 0; reg < 4; ++reg) {
    float linv = 1.0f / __shfl(l_run, (u << 2) + reg);
    size_t ob = ((size_t)b * L + (qt << 4) + (u << 2) + reg) * 128 + h * 32;
    O[ob + r] = f2bfs(o0[reg] * linv);
    O[ob + 16 + r] = f2bfs(o1[reg] * linv);
  }
}

// ---------------- direct 3x3 conv, 4 co per thread ----------------
template <int CIN>
__global__ void conv3x3_kernel(const float* __restrict__ in, const float* __restrict__ w,
                               float* __restrict__ out) {
  int x = threadIdx.x & 63;
  int y = (blockIdx.x << 2) + (threadIdx.x >> 6);
  int cog = blockIdx.y;
  int b = blockIdx.z;
  float acc0 = 0, acc1 = 0, acc2 = 0, acc3 = 0;
  const float* ip = in + (size_t)b * CIN * L;
  const float* wp = w + (size_t)cog * 4 * CIN * 9;
  for (int ci = 0; ci < CIN; ++ci) {
    const float* irow = ip + (size_t)ci * L;
    const float* wc = wp + (size_t)ci * 9;
#pragma unroll
    for (int ky = 0; ky < 3; ++ky) {
      int yy = y + ky - 1;
      if (yy < 0 || yy > 63) continue;
      const float* r = irow + yy * 64;
#pragma unroll
      for (int kx = 0; kx < 3; ++kx) {
        int xx = x + kx - 1;
        if (xx < 0 || xx > 63) continue;
        float v = r[xx];
        int t = ky * 3 + kx;
        acc0 += v * wc[t];
        acc1 += v * wc[CIN * 9 + t];
        acc2 += v * wc[2 * CIN * 9 + t];
        acc3 += v * wc[3 * CIN * 9 + t];
      }
    }
  }
  size_t ob = ((size_t)(b * 128 + (cog << 2)) * L) + y * 64 + x;
  out[ob] = acc0; out[ob + L] = acc1; out[ob + 2 * L] = acc2; out[ob + 3 * L] = acc3;
}

// ---------------- BN batch stats (training mode) ----------------
__global__ void bnstats_kernel(const float* __restrict__ x, float* __restrict__ mean, float* __restrict__ rstd) {
  __shared__ float rs[256], rq[256];
  int c = blockIdx.x, tid = threadIdx.x;
  float s = 0, q = 0;
  for (int i = tid; i < BCH * L; i += 256) {
    int b = i >> 12, p = i & 4095;
    float v = x[((size_t)(b * 128 + c)) * L + p];
    s += v; q += v * v;
  }
  rs[tid] = s; rq[tid] = q; __syncthreads();
  for (int st = 128; st > 0; st >>= 1) { if (tid < st) { rs[tid] += rs[tid + st]; rq[tid] += rq[tid + st]; } __syncthreads(); }
  if (tid == 0) {
    float m = rs[0] / (float)(BCH * L);
    float v = rq[0] / (float)(BCH * L) - m * m;
    mean[c] = m;
    rstd[c] = rsqrtf(v + 1e-5f);
  }
}

__global__ void bnapply_kernel(float* __restrict__ x, const float* __restrict__ mean, const float* __restrict__ rstd,
                               const float* __restrict__ g, const float* __restrict__ bb) {
  int i = blockIdx.x * 256 + threadIdx.x;
  int c = (i >> 12) & 127;
  float v = x[i];
  float y = g[c] * (v - mean[c]) * rstd[c] + bb[c];
  x[i] = fmaxf(y, 0.0f);
}

// ---------------- fused 1x1 heads ----------------
__global__ void head_kernel(const float* __restrict__ feat,
                            const float* __restrict__ w1, const float* __restrict__ b1,
                            const float* __restrict__ w2, const float* __restrict__ b2,
                            const float* __restrict__ wo, const float* __restrict__ bo,
                            float* __restrict__ score, float* __restrict__ plog) {
  __shared__ float f[128][64];
  __shared__ float r1[4][64], r2[4][64];
  int by = blockIdx.x; int b = by >> 6, y = by & 63;
  int tid = threadIdx.x;
  int x = tid & 63, g4 = tid >> 6;
  for (int c = g4; c < 128; c += 4)
    f[c][x] = feat[((size_t)(b * 128 + c)) * L + y * 64 + x];
  __syncthreads();
  int cb = g4 * 32;
  float a[32];
#pragma unroll
  for (int i = 0; i < 32; ++i) a[i] = b1[cb + i];
  for (int ci = 0; ci < 128; ++ci) {
    float fv = f[ci][x];
#pragma unroll
    for (int i = 0; i < 32; ++i) a[i] += w1[(size_t)(cb + i) * 128 + ci] * fv;
  }
  float sp = 0.0f;
#pragma unroll
  for (int i = 0; i < 32; ++i) sp += w2[cb + i] * fmaxf(a[i], 0.0f);
  float plp = 0.0f;
#pragma unroll
  for (int i = 0; i < 32; ++i) plp += wo[cb + i] * f[cb + i][x];
  r1[g4][x] = sp; r2[g4][x] = plp;
  __syncthreads();
  if (tid < 64) {
    int xx = tid;
    float s = r1[0][xx] + r1[1][xx] + r1[2][xx] + r1[3][xx] + b2[0];
    float pl = r2[0][xx] + r2[1][xx] + r2[2][xx] + r2[3][xx] + bo[0];
    score[(size_t)b * L + y * 64 + xx] = s;
    plog[(size_t)b * L + y * 64 + xx] = pl;
  }
}

// ---------------- masked softmax + attention maps + bag ----------------
__global__ void finalize_kernel(const float* __restrict__ score, const float* __restrict__ plog,
                                const int* __restrict__ zone, const int* __restrict__ cats,
                                float* __restrict__ maps, float* __restrict__ bag_ws) {
  __shared__ float sc[4096];
  __shared__ float red[256];
  __shared__ int ired[256];
  int b = blockIdx.x, tid = threadIdx.x;
  int cat = cats[b];
  float lmax = -3e38f; int lhas = 0;
  for (int p = tid; p < 4096; p += 256) {
    int z = zone[(size_t)b * 4096 + p];
    int m = (z == cat) && (z > 0);
    float s = m ? score[(size_t)b * 4096 + p] : -1e9f;
    sc[p] = s; lmax = fmaxf(lmax, s); lhas |= m;
  }
  red[tid] = lmax; ired[tid] = lhas; __syncthreads();
  for (int st = 128; st > 0; st >>= 1) {
    if (tid < st) { red[tid] = fmaxf(red[tid], red[tid + st]); ired[tid] |= ired[tid + st]; }
    __syncthreads();
  }
  float gmax = red[0]; int has = ired[0];
  __syncthreads();
  float lsum = 0;
  for (int p = tid; p < 4096; p += 256) {
    float e = __expf(sc[p] - gmax);
    sc[p] = e; lsum += e;
  }
  red[tid] = lsum; __syncthreads();
  for (int st = 128; st > 0; st >>= 1) { if (tid < st) red[tid] += red[tid + st]; __syncthreads(); }
  float inv = 1.0f / red[0];
  __syncthreads();
  float lbag = 0;
  for (int p = tid; p < 4096; p += 256) {
    float w = sc[p] * inv;
    maps[(size_t)b * 4096 + p] = has ? w : 0.0f;
    int z = zone[(size_t)b * 4096 + p];
    if ((z == cat) && (z > 0)) lbag += plog[(size_t)b * 4096 + p] * w;
  }
  red[tid] = lbag; __syncthreads();
  for (int st = 128; st > 0; st >>= 1) { if (tid < st) red[tid] += red[tid + st]; __syncthreads(); }
  if (tid == 0) bag_ws[b] = has ? red[0] : 0.0f;
}

__global__ void loss_kernel(const float* __restrict__ bag_ws, const float* __restrict__ labels,
                            float* __restrict__ out) {
  if (threadIdx.x == 0 && blockIdx.x == 0) {
    float t = 0;
    for (int b = 0; b < BCH; ++b) {
      float x = bag_ws[b];
      float sp = fmaxf(x, 0.0f) + log1pf(expf(-fabsf(x)));
      t += sp - x * labels[b];
    }
    out[0] = t / (float)BCH;
  }
}

extern "C" void kernel_launch(void* const* d_in, const int* in_sizes, int n_in,
                              void* d_out, int out_size, void* d_ws, size_t ws_size,
                              hipStream_t stream) {
  (void)in_sizes; (void)n_in; (void)out_size; (void)ws_size;
  const float* state = (const float*)d_in[0];
  const float* trig  = (const float*)d_in[1];
  const float* gnn   = (const float*)d_in[2];
  const int*   zone  = (const int*)d_in[3];
  const int*   cats  = (const int*)d_in[4];
  const float* labels = (const float*)d_in[5];
  const float* s2t_qkv_w = (const float*)d_in[6];
  const float* s2t_qkv_b = (const float*)d_in[7];
  const float* s2t_out_w = (const float*)d_in[8];
  const float* s2t_out_b = (const float*)d_in[9];
  const float* t2s_qkv_w = (const float*)d_in[10];
  const float* t2s_qkv_b = (const float*)d_in[11];
  const float* t2s_out_w = (const float*)d_in[12];
  const float* t2s_out_b = (const float*)d_in[13];
  const float* fconv1_w = (const float*)d_in[14];
  const float* fbn1_g = (const float*)d_in[15];
  const float* fbn1_b = (const float*)d_in[16];
  const float* fconv2_w = (const float*)d_in[17];
  const float* fbn2_g = (const float*)d_in[18];
  const float* fbn2_b = (const float*)d_in[19];
  const float* outc_w = (const float*)d_in[20];
  const float* outc_b = (const float*)d_in[21];
  const float* attn1_w = (const float*)d_in[22];
  const float* attn1_b = (const float*)d_in[23];
  const float* attn2_w = (const float*)d_in[24];
  const float* attn2_b = (const float*)d_in[25];

  float* ws = (float*)d_ws;
  const size_t NBP = (size_t)BCH * L * 128; // 1,048,576
  size_t o = 0;
  float* fused = ws + o; o += (size_t)BCH * FUSEDC * L;
  float* c1 = ws + o; o += NBP;
  float* c2 = ws + o; o += NBP;
  float* stats = ws + o; o += 512;
  float* score = ws + o; o += (size_t)BCH * L;
  float* plog = ws + o; o += (size_t)BCH * L;
  float* bag = ws + o; o += 8;
  // bf16 buffers (NBP shorts = NBP/2 float slots each)
  short* Xs = (short*)(ws + o); o += NBP / 2;
  short* Xt = (short*)(ws + o); o += NBP / 2;
  short* qsb = (short*)(ws + o); o += NBP / 2;
  short* ksb = (short*)(ws + o); o += NBP / 2;
  short* qtb = (short*)(ws + o); o += NBP / 2;
  short* ktb = (short*)(ws + o); o += NBP / 2;
  short* vTsb = (short*)(ws + o); o += NBP / 2;
  short* vTtb = (short*)(ws + o); o += NBP / 2;
  short* aosb = (short*)(ws + o); o += NBP / 2;
  short* aotb = (short*)(ws + o); o += NBP / 2;
  short* wSb = (short*)(ws + o); o += 24576;   // 49152 shorts
  short* wTb = (short*)(ws + o); o += 24576;
  short* woSb = (short*)(ws + o); o += 8192;   // 16384 shorts
  short* woTb = (short*)(ws + o); o += 8192;

  prep_weights<<<192, 256, 0, stream>>>(s2t_qkv_w, t2s_qkv_w, s2t_out_w, t2s_out_w,
                                        wSb, wTb, woSb, woTb);
  transpose_kernel<<<dim3(128, 4, BCH), 256, 0, stream>>>(state, Xs);
  transpose_kernel<<<dim3(128, 4, BCH), 256, 0, stream>>>(trig, Xt);

  gemm_qk<<<dim3(128, 4), 256, 0, stream>>>(Xs, Xt, wSb, wTb, s2t_qkv_b, t2s_qkv_b,
                                            qsb, ksb, qtb, ktb);
  gemm_vo<<<dim3(128, 2), 256, 0, stream>>>(Xs, Xt, aosb, aotb, wSb, wTb, woSb, woTb,
                                            s2t_qkv_b, t2s_qkv_b, s2t_out_b, t2s_out_b,
                                            vTsb, vTtb, fused, 0);

  flash_attn_kernel<<<dim3(64, NHEAD, BCH), 256, 0, stream>>>(qsb, ksb, vTsb, aosb);
  flash_attn_kernel<<<dim3(64, NHEAD, BCH), 256, 0, stream>>>(qtb, ktb, vTtb, aotb);

  gemm_vo<<<dim3(128, 2), 256, 0, stream>>>(Xs, Xt, aosb, aotb, wSb, wTb, woSb, woTb,
                                            s2t_qkv_b, t2s_qkv_b, s2t_out_b, t2s_out_b,
                                            vTsb, vTtb, fused, 2);
  copy_gnn<<<32, 256, 0, stream>>>(gnn, fused);

  conv3x3_kernel<257><<<dim3(16, 32, BCH), 256, 0, stream>>>(fused, fconv1_w, c1);
  bnstats_kernel<<<128, 256, 0, stream>>>(c1, stats, stats + 128);
  bnapply_kernel<<<4096, 256, 0, stream>>>(c1, stats, stats + 128, fbn1_g, fbn1_b);

  conv3x3_kernel<128><<<dim3(16, 32, BCH), 256, 0, stream>>>(c1, fconv2_w, c2);
  bnstats_kernel<<<128, 256, 0, stream>>>(c2, stats + 256, stats + 384);
  bnapply_kernel<<<4096, 256, 0, stream>>>(c2, stats + 256, stats + 384, fbn2_g, fbn2_b);

  head_kernel<<<BCH * 64, 256, 0, stream>>>(c2, attn1_w, attn1_b, attn2_w, attn2_b,
                                            outc_w, outc_b, score, plog);

  finalize_kernel<<<BCH, 256, 0, stream>>>(score, plog, zone, cats, (float*)d_out + 1, bag);
  loss_kernel<<<1, 64, 0, stream>>>(bag, labels, (float*)d_out);
}

// Round 4
// 525.819 us; speedup vs baseline: 11.0047x; 1.7295x over previous
//
#include <hip/hip_runtime.h>
#include <hip/hip_bf16.h>
#include <math.h>

#define L 4096
#define ECH 128
#define BCH 2
#define NHEAD 4
#define FUSEDC 257
#define CPAD 288   // fused channels padded to multiple of 32 (16B-aligned rows)

typedef __attribute__((ext_vector_type(8))) short bs8;
typedef __attribute__((ext_vector_type(4))) short bs4;
typedef __attribute__((ext_vector_type(4))) float fx4;

// round-to-nearest-even f32 -> bf16 bits
static __device__ __forceinline__ short f2bfs(float x) {
  unsigned u = __float_as_uint(x);
  u += 0x7fffu + ((u >> 16) & 1u);
  return (short)(u >> 16);
}

// ---------------- transpose (B,128,4096) f32 -> (B,4096,128) bf16 ----------------
__global__ void transpose_kernel(const float* __restrict__ in, short* __restrict__ out) {
  __shared__ float t[32][33];
  int b = blockIdx.z;
  int bx = blockIdx.x * 32;
  int by = blockIdx.y * 32;
  int tx = threadIdx.x & 31, ty = threadIdx.x >> 5;
  const float* ip = in + (size_t)b * ECH * L;
  short* op = out + (size_t)b * L * ECH;
#pragma unroll
  for (int r = ty; r < 32; r += 8)
    t[r][tx] = ip[(size_t)(by + r) * L + bx + tx];
  __syncthreads();
#pragma unroll
  for (int r = ty; r < 32; r += 8)
    op[(size_t)(bx + r) * ECH + by + tx] = f2bfs(t[tx][r]);
}

// ---------------- attention weight prep: f32 -> bf16 (Q rows pre-scaled) ----------
__global__ void prep_weights(const float* __restrict__ wS, const float* __restrict__ wT,
                             const float* __restrict__ woS, const float* __restrict__ woT,
                             short* __restrict__ wSb, short* __restrict__ wTb,
                             short* __restrict__ woSb, short* __restrict__ woTb) {
  int i = blockIdx.x * 256 + threadIdx.x;
  const float SC = 0.17677669529663687f;
  if (i < 49152) {
    float s = (i < 16384) ? SC : 1.0f;
    wSb[i] = f2bfs(wS[i] * s);
    wTb[i] = f2bfs(wT[i] * s);
  }
  if (i < 16384) {
    woSb[i] = f2bfs(woS[i]);
    woTb[i] = f2bfs(woT[i]);
  }
}

// ---------------- conv weight prep -> bf16 [tap][co][ci_pad] ----------------
__global__ void prep_conv1(const float* __restrict__ w, short* __restrict__ W1b) {
  int i = blockIdx.x * 256 + threadIdx.x; // 9*128*288 = 331776
  int ci = i % CPAD; int rest = i / CPAD; int co = rest & 127; int tap = rest >> 7;
  W1b[i] = (ci < FUSEDC) ? f2bfs(w[(co * FUSEDC + ci) * 9 + tap]) : (short)0;
}

__global__ void prep_conv2(const float* __restrict__ w, short* __restrict__ W2b) {
  int i = blockIdx.x * 256 + threadIdx.x; // 9*128*128 = 147456
  int ci = i & 127; int co = (i >> 7) & 127; int tap = i >> 14;
  W2b[i] = f2bfs(w[(co * 128 + ci) * 9 + tap]);
}

// ---------------- MFMA GEMM A=X,B=W^T: Q (pixel-major) / K (head-packed) ----------
__global__ void __launch_bounds__(256)
gemm_qk(const short* __restrict__ Xs, const short* __restrict__ Xt,
        const short* __restrict__ wSb, const short* __restrict__ wTb,
        const float* __restrict__ bS, const float* __restrict__ bT,
        short* __restrict__ qs, short* __restrict__ ks,
        short* __restrict__ qt, short* __restrict__ kt) {
  const float SC = 0.17677669529663687f;
  int unit = blockIdx.y;
  const short* X; const short* W; const float* bias; short* out; float scale; int isK;
  switch (unit) {
    case 0: X = Xs; W = wSb;         bias = bS;       out = qs; scale = SC;  isK = 0; break;
    case 1: X = Xt; W = wSb + 16384; bias = bS + 128; out = ks; scale = 1.f; isK = 1; break;
    case 2: X = Xt; W = wTb;         bias = bT;       out = qt; scale = SC;  isK = 0; break;
    default:X = Xs; W = wTb + 16384; bias = bT + 128; out = kt; scale = 1.f; isK = 1; break;
  }
  int tid = threadIdx.x;
  int wv = tid >> 6, lane = tid & 63, u = lane >> 4, r = lane & 15;
  int pblk = blockIdx.x * 64 + wv * 16;
  const short* xrow = X + (size_t)(pblk + r) * 128;
  fx4 acc[8] = {};
#pragma unroll
  for (int ksx = 0; ksx < 4; ++ksx) {
    int k0 = ksx * 32 + u * 8;
    bs8 a = *(const bs8*)(xrow + k0);
    const short* wp = W + (size_t)r * 128 + k0;
#pragma unroll
    for (int t = 0; t < 8; ++t) {
      bs8 wf = *(const bs8*)(wp + (size_t)t * 16 * 128);
      acc[t] = __builtin_amdgcn_mfma_f32_16x16x32_bf16(a, wf, acc[t], 0, 0, 0);
    }
  }
  if (isK) {
#pragma unroll
    for (int t = 0; t < 8; ++t) {
      int och = t * 16 + r, h = och >> 5, d = och & 31;
      float bv = bias[och];
#pragma unroll
      for (int reg = 0; reg < 4; ++reg) {
        int p = pblk + u * 4 + reg;
        int b = p >> 12, pl = p & 4095;
        out[(((size_t)(b * NHEAD + h) * L + pl) << 5) + d] = f2bfs(acc[t][reg] + bv);
      }
    }
  } else {
#pragma unroll
    for (int t = 0; t < 8; ++t) {
      float bv = bias[t * 16 + r] * scale;
#pragma unroll
      for (int reg = 0; reg < 4; ++reg) {
        int p = pblk + u * 4 + reg;
        out[(size_t)p * 128 + t * 16 + r] = f2bfs(acc[t][reg] + bv);
      }
    }
  }
}

// ---------------- MFMA GEMM A=W,B=X^T: V into V^T (b,h,d,L) bf16 ----------------
__global__ void __launch_bounds__(256)
gemm_v(const short* __restrict__ Xs, const short* __restrict__ Xt,
       const short* __restrict__ wSb, const short* __restrict__ wTb,
       const float* __restrict__ bS, const float* __restrict__ bT,
       short* __restrict__ vTs, short* __restrict__ vTt) {
  int unit = blockIdx.y;
  const short* X = unit ? Xs : Xt;
  const short* W = unit ? (wTb + 32768) : (wSb + 32768);
  const float* bias = unit ? (bT + 256) : (bS + 256);
  short* out = unit ? vTt : vTs;
  int tid = threadIdx.x;
  int wv = tid >> 6, lane = tid & 63, u = lane >> 4, r = lane & 15;
  int pblk = blockIdx.x * 64 + wv * 16;
  const short* xrow = X + (size_t)(pblk + r) * 128;
  fx4 acc[8] = {};
#pragma unroll
  for (int ksx = 0; ksx < 4; ++ksx) {
    int k0 = ksx * 32 + u * 8;
    bs8 xb = *(const bs8*)(xrow + k0);
    const short* wp = W + (size_t)r * 128 + k0;
#pragma unroll
    for (int t = 0; t < 8; ++t) {
      bs8 wf = *(const bs8*)(wp + (size_t)t * 16 * 128);
      acc[t] = __builtin_amdgcn_mfma_f32_16x16x32_bf16(wf, xb, acc[t], 0, 0, 0);
    }
  }
  int p = pblk + r;
  int b = p >> 12, pl = p & 4095;
#pragma unroll
  for (int t = 0; t < 8; ++t) {
#pragma unroll
    for (int reg = 0; reg < 4; ++reg) {
      int och = t * 16 + u * 4 + reg;
      int h = och >> 5, d = och & 31;
      out[((size_t)(b * NHEAD + h) * 32 + d) * L + pl] = f2bfs(acc[t][reg] + bias[och]);
    }
  }
}

// ---------------- out-projection -> fusedPM (pixel-major bf16, CPAD stride) -------
__global__ void __launch_bounds__(256)
gemm_o(const short* __restrict__ aosb, const short* __restrict__ aotb,
       const short* __restrict__ woSb, const short* __restrict__ woTb,
       const float* __restrict__ boS, const float* __restrict__ boT,
       short* __restrict__ fusedPM) {
  int unit = blockIdx.y;
  const short* X = unit ? aotb : aosb;
  const short* W = unit ? woTb : woSb;
  const float* bias = unit ? boT : boS;
  int ochbase = unit ? 128 : 0;
  int tid = threadIdx.x;
  int wv = tid >> 6, lane = tid & 63, u = lane >> 4, r = lane & 15;
  int pblk = blockIdx.x * 64 + wv * 16;
  const short* xrow = X + (size_t)(pblk + r) * 128;
  fx4 acc[8] = {};
#pragma unroll
  for (int ksx = 0; ksx < 4; ++ksx) {
    int k0 = ksx * 32 + u * 8;
    bs8 a = *(const bs8*)(xrow + k0);
    const short* wp = W + (size_t)r * 128 + k0;
#pragma unroll
    for (int t = 0; t < 8; ++t) {
      bs8 wf = *(const bs8*)(wp + (size_t)t * 16 * 128);
      acc[t] = __builtin_amdgcn_mfma_f32_16x16x32_bf16(a, wf, acc[t], 0, 0, 0);
    }
  }
#pragma unroll
  for (int t = 0; t < 8; ++t) {
    float bv = bias[t * 16 + r];
#pragma unroll
    for (int reg = 0; reg < 4; ++reg) {
      int p = pblk + u * 4 + reg;
      fusedPM[(size_t)p * CPAD + ochbase + t * 16 + r] = f2bfs(acc[t][reg] + bv);
    }
  }
}

__global__ void copy_gnn_pm(const float* __restrict__ gnn, short* __restrict__ fusedPM) {
  int i = blockIdx.x * 256 + threadIdx.x; // 8192*32
  int p = i >> 5, j = i & 31;
  fusedPM[(size_t)p * CPAD + 256 + j] = (j == 0) ? f2bfs(gnn[p]) : (short)0;
}

// ---------------- bf16 MFMA flash attention (K head-packed, O bf16 pm) ------------
__global__ void __launch_bounds__(256)
flash_attn_kernel(const short* __restrict__ Q, const short* __restrict__ K,
                  const short* __restrict__ VT, short* __restrict__ O) {
  int tid = threadIdx.x;
  int wid = tid >> 6, lane = tid & 63;
  int u = lane >> 4, r = lane & 15;
  int h = blockIdx.y, b = blockIdx.z;
  int qt = (blockIdx.x << 2) + wid;
  bs8 qf = *(const bs8*)(Q + ((size_t)(b * L + (qt << 4) + r) * 128 + h * 32 + u * 8));
  const short* Kb = K + (((size_t)(b * NHEAD + h) * L) << 5) + u * 8;
  const short* Vb = VT + ((size_t)(b * NHEAD + h) * 32) * (size_t)L;
  const short* v0p = Vb + (size_t)r * L + (u << 2);
  const short* v1p = Vb + (size_t)(16 + r) * L + (u << 2);
  fx4 o0 = {0.f, 0.f, 0.f, 0.f}, o1 = {0.f, 0.f, 0.f, 0.f};
  float m_run = -3.0e38f, l_run = 0.0f;
  for (int k0 = 0; k0 < L; k0 += 32) {
    bs8 a0 = *(const bs8*)(Kb + (((size_t)(k0 + r)) << 5));
    bs8 a1 = *(const bs8*)(Kb + (((size_t)(k0 + 16 + r)) << 5));
    fx4 zz = {0.f, 0.f, 0.f, 0.f};
    fx4 s0 = __builtin_amdgcn_mfma_f32_16x16x32_bf16(a0, qf, zz, 0, 0, 0);
    fx4 s1 = __builtin_amdgcn_mfma_f32_16x16x32_bf16(a1, qf, zz, 0, 0, 0);
    bs4 w0lo = *(const bs4*)(v0p + k0);
    bs4 w0hi = *(const bs4*)(v0p + k0 + 16);
    bs4 w1lo = *(const bs4*)(v1p + k0);
    bs4 w1hi = *(const bs4*)(v1p + k0 + 16);
    bs8 vb0 = __builtin_shufflevector(w0lo, w0hi, 0, 1, 2, 3, 4, 5, 6, 7);
    bs8 vb1 = __builtin_shufflevector(w1lo, w1hi, 0, 1, 2, 3, 4, 5, 6, 7);
    float mx = fmaxf(fmaxf(s0[0], s0[1]), fmaxf(s0[2], s0[3]));
    mx = fmaxf(mx, fmaxf(fmaxf(s1[0], s1[1]), fmaxf(s1[2], s1[3])));
    mx = fmaxf(mx, __shfl_xor(mx, 16));
    mx = fmaxf(mx, __shfl_xor(mx, 32));
    float m_new = fmaxf(m_run, mx);
    float fsc = __expf(m_run - m_new);
    fx4 p0, p1;
#pragma unroll
    for (int i = 0; i < 4; ++i) { p0[i] = __expf(s0[i] - m_new); p1[i] = __expf(s1[i] - m_new); }
    float ls = (p0[0] + p0[1]) + (p0[2] + p0[3]) + (p1[0] + p1[1]) + (p1[2] + p1[3]);
    ls += __shfl_xor(ls, 16);
    ls += __shfl_xor(ls, 32);
    l_run = l_run * fsc + ls;
    m_run = m_new;
#pragma unroll
    for (int reg = 0; reg < 4; ++reg) {
      float fo = __shfl(fsc, (u << 2) + reg);
      o0[reg] *= fo; o1[reg] *= fo;
    }
    bs8 pa;
#pragma unroll
    for (int i = 0; i < 4; ++i) { pa[i] = f2bfs(p0[i]); pa[i + 4] = f2bfs(p1[i]); }
    o0 = __builtin_amdgcn_mfma_f32_16x16x32_bf16(pa, vb0, o0, 0, 0, 0);
    o1 = __builtin_amdgcn_mfma_f32_16x16x32_bf16(pa, vb1, o1, 0, 0, 0);
  }
#pragma unroll
  for (int reg = 0; reg < 4; ++reg) {
    float linv = 1.0f / __shfl(l_run, (u << 2) + reg);
    size_t ob = ((size_t)b * L + (qt << 4) + (u << 2) + reg) * 128 + h * 32;
    O[ob + r] = f2bfs(o0[reg] * linv);
    O[ob + 16 + r] = f2bfs(o1[reg] * linv);
  }
}

// ---------------- conv1 3x3 via MFMA: fusedPM (8192xCPAD bf16) -> c1 pm f32 -------
__global__ void __launch_bounds__(128)
conv1_mfma(const short* __restrict__ X, const short* __restrict__ W,
           float* __restrict__ out) {
  int tid = threadIdx.x;
  int wv = tid >> 6, lane = tid & 63, u = lane >> 4, r = lane & 15;
  int pblk = blockIdx.x * 32 + wv * 16;   // 256 blocks x 2 waves x 16 px
  int b = pblk >> 12, y = (pblk & 4095) >> 6, x0 = pblk & 63;
  fx4 acc[8] = {};
  for (int tap = 0; tap < 9; ++tap) {
    int dy = tap / 3 - 1, dx = tap % 3 - 1;
    int yy = y + dy;
    if (yy < 0 || yy > 63) { __syncthreads(); continue; }
    int xx = x0 + r + dx;
    bool valid = (xx >= 0) && (xx <= 63);
    const short* xrow = X + (size_t)((b << 12) + (yy << 6) + x0 + dx + r) * CPAD;
    const short* wtap = W + ((size_t)tap * 128 + r) * CPAD;
#pragma unroll
    for (int kc = 0; kc < 9; ++kc) {
      int k0 = kc * 32 + u * 8;
      bs8 a = {};
      if (valid) a = *(const bs8*)(xrow + k0);
#pragma unroll
      for (int t = 0; t < 8; ++t) {
        bs8 wf = *(const bs8*)(wtap + (size_t)t * 16 * CPAD + k0);
        acc[t] = __builtin_amdgcn_mfma_f32_16x16x32_bf16(a, wf, acc[t], 0, 0, 0);
      }
    }
    __syncthreads(); // keep the 2 waves in lockstep for L1 weight reuse
  }
#pragma unroll
  for (int t = 0; t < 8; ++t)
#pragma unroll
    for (int reg = 0; reg < 4; ++reg)
      out[(size_t)(pblk + u * 4 + reg) * 128 + t * 16 + r] = acc[t][reg];
}

// ---------------- conv2 3x3 via MFMA: X2 (8192x128 bf16 pm) -> c2 channel-major ---
__global__ void __launch_bounds__(128)
conv2_mfma(const short* __restrict__ X, const short* __restrict__ W,
           float* __restrict__ out) {
  int tid = threadIdx.x;
  int wv = tid >> 6, lane = tid & 63, u = lane >> 4, r = lane & 15;
  int pblk = blockIdx.x * 32 + wv * 16;
  int b = pblk >> 12, y = (pblk & 4095) >> 6, x0 = pblk & 63;
  fx4 acc[8] = {};
  for (int tap = 0; tap < 9; ++tap) {
    int dy = tap / 3 - 1, dx = tap % 3 - 1;
    int yy = y + dy;
    if (yy < 0 || yy > 63) { __syncthreads(); continue; }
    int xx = x0 + r + dx;
    bool valid = (xx >= 0) && (xx <= 63);
    const short* xrow = X + (size_t)((b << 12) + (yy << 6) + x0 + dx + r) * 128;
    const short* wtap = W + ((size_t)tap * 128 + r) * 128;
#pragma unroll
    for (int kc = 0; kc < 4; ++kc) {
      int k0 = kc * 32 + u * 8;
      bs8 xb = {};
      if (valid) xb = *(const bs8*)(xrow + k0);
#pragma unroll
      for (int t = 0; t < 8; ++t) {
        bs8 wf = *(const bs8*)(wtap + (size_t)t * 16 * 128 + k0);
        acc[t] = __builtin_amdgcn_mfma_f32_16x16x32_bf16(wf, xb, acc[t], 0, 0, 0);
      }
    }
    __syncthreads();
  }
  int px = y * 64 + x0 + r;
#pragma unroll
  for (int t = 0; t < 8; ++t)
#pragma unroll
    for (int reg = 0; reg < 4; ++reg) {
      int och = t * 16 + u * 4 + reg;
      out[((size_t)(b * 128 + och) << 12) + px] = acc[t][reg];
    }
}

// ---------------- BN stats over pixel-major f32 ----------------
__global__ void bnstats_pm(const float* __restrict__ x, float* __restrict__ mean,
                           float* __restrict__ rstd) {
  __shared__ float rs[256], rq[256];
  int c = blockIdx.x, tid = threadIdx.x;
  float s = 0, q = 0;
  for (int p = tid; p < BCH * L; p += 256) {
    float v = x[(size_t)p * 128 + c];
    s += v; q += v * v;
  }
  rs[tid] = s; rq[tid] = q; __syncthreads();
  for (int st = 128; st > 0; st >>= 1) { if (tid < st) { rs[tid] += rs[tid + st]; rq[tid] += rq[tid + st]; } __syncthreads(); }
  if (tid == 0) {
    float m = rs[0] / (float)(BCH * L);
    float v = rq[0] / (float)(BCH * L) - m * m;
    mean[c] = m;
    rstd[c] = rsqrtf(v + 1e-5f);
  }
}

// BN apply + ReLU on pixel-major f32 -> bf16 pixel-major
__global__ void bnapply_pm(const float* __restrict__ x, const float* __restrict__ mean,
                           const float* __restrict__ rstd, const float* __restrict__ g,
                           const float* __restrict__ bb, short* __restrict__ out) {
  int i = blockIdx.x * 256 + threadIdx.x;
  int c = i & 127;
  float v = x[i];
  out[i] = f2bfs(fmaxf(g[c] * (v - mean[c]) * rstd[c] + bb[c], 0.0f));
}

// ---------------- BN stats / apply, channel-major (for c2) ----------------
__global__ void bnstats_kernel(const float* __restrict__ x, float* __restrict__ mean, float* __restrict__ rstd) {
  __shared__ float rs[256], rq[256];
  int c = blockIdx.x, tid = threadIdx.x;
  float s = 0, q = 0;
  for (int i = tid; i < BCH * L; i += 256) {
    int b = i >> 12, p = i & 4095;
    float v = x[((size_t)(b * 128 + c)) * L + p];
    s += v; q += v * v;
  }
  rs[tid] = s; rq[tid] = q; __syncthreads();
  for (int st = 128; st > 0; st >>= 1) { if (tid < st) { rs[tid] += rs[tid + st]; rq[tid] += rq[tid + st]; } __syncthreads(); }
  if (tid == 0) {
    float m = rs[0] / (float)(BCH * L);
    float v = rq[0] / (float)(BCH * L) - m * m;
    mean[c] = m;
    rstd[c] = rsqrtf(v + 1e-5f);
  }
}

__global__ void bnapply_kernel(float* __restrict__ x, const float* __restrict__ mean, const float* __restrict__ rstd,
                               const float* __restrict__ g, const float* __restrict__ bb) {
  int i = blockIdx.x * 256 + threadIdx.x;
  int c = (i >> 12) & 127;
  float v = x[i];
  float y = g[c] * (v - mean[c]) * rstd[c] + bb[c];
  x[i] = fmaxf(y, 0.0f);
}

// ---------------- fused 1x1 heads ----------------
__global__ void head_kernel(const float* __restrict__ feat,
                            const float* __restrict__ w1, const float* __restrict__ b1,
                            const float* __restrict__ w2, const float* __restrict__ b2,
                            const float* __restrict__ wo, const float* __restrict__ bo,
                            float* __restrict__ score, float* __restrict__ plog) {
  __shared__ float f[128][64];
  __shared__ float r1[4][64], r2[4][64];
  int by = blockIdx.x; int b = by >> 6, y = by & 63;
  int tid = threadIdx.x;
  int x = tid & 63, g4 = tid >> 6;
  for (int c = g4; c < 128; c += 4)
    f[c][x] = feat[((size_t)(b * 128 + c)) * L + y * 64 + x];
  __syncthreads();
  int cb = g4 * 32;
  float a[32];
#pragma unroll
  for (int i = 0; i < 32; ++i) a[i] = b1[cb + i];
  for (int ci = 0; ci < 128; ++ci) {
    float fv = f[ci][x];
#pragma unroll
    for (int i = 0; i < 32; ++i) a[i] += w1[(size_t)(cb + i) * 128 + ci] * fv;
  }
  float sp = 0.0f;
#pragma unroll
  for (int i = 0; i < 32; ++i) sp += w2[cb + i] * fmaxf(a[i], 0.0f);
  float plp = 0.0f;
#pragma unroll
  for (int i = 0; i < 32; ++i) plp += wo[cb + i] * f[cb + i][x];
  r1[g4][x] = sp; r2[g4][x] = plp;
  __syncthreads();
  if (tid < 64) {
    int xx = tid;
    float s = r1[0][xx] + r1[1][xx] + r1[2][xx] + r1[3][xx] + b2[0];
    float pl = r2[0][xx] + r2[1][xx] + r2[2][xx] + r2[3][xx] + bo[0];
    score[(size_t)b * L + y * 64 + xx] = s;
    plog[(size_t)b * L + y * 64 + xx] = pl;
  }
}

// ---------------- masked softmax + attention maps + bag ----------------
__global__ void finalize_kernel(const float* __restrict__ score, const float* __restrict__ plog,
                                const int* __restrict__ zone, const int* __restrict__ cats,
                                float* __restrict__ maps, float* __restrict__ bag_ws) {
  __shared__ float sc[4096];
  __shared__ float red[256];
  __shared__ int ired[256];
  int b = blockIdx.x, tid = threadIdx.x;
  int cat = cats[b];
  float lmax = -3e38f; int lhas = 0;
  for (int p = tid; p < 4096; p += 256) {
    int z = zone[(size_t)b * 4096 + p];
    int m = (z == cat) && (z > 0);
    float s = m ? score[(size_t)b * 4096 + p] : -1e9f;
    sc[p] = s; lmax = fmaxf(lmax, s); lhas |= m;
  }
  red[tid] = lmax; ired[tid] = lhas; __syncthreads();
  for (int st = 128; st > 0; st >>= 1) {
    if (tid < st) { red[tid] = fmaxf(red[tid], red[tid + st]); ired[tid] |= ired[tid + st]; }
    __syncthreads();
  }
  float gmax = red[0]; int has = ired[0];
  __syncthreads();
  float lsum = 0;
  for (int p = tid; p < 4096; p += 256) {
    float e = __expf(sc[p] - gmax);
    sc[p] = e; lsum += e;
  }
  red[tid] = lsum; __syncthreads();
  for (int st = 128; st > 0; st >>= 1) { if (tid < st) red[tid] += red[tid + st]; __syncthreads(); }
  float inv = 1.0f / red[0];
  __syncthreads();
  float lbag = 0;
  for (int p = tid; p < 4096; p += 256) {
    float w = sc[p] * inv;
    maps[(size_t)b * 4096 + p] = has ? w : 0.0f;
    int z = zone[(size_t)b * 4096 + p];
    if ((z == cat) && (z > 0)) lbag += plog[(size_t)b * 4096 + p] * w;
  }
  red[tid] = lbag; __syncthreads();
  for (int st = 128; st > 0; st >>= 1) { if (tid < st) red[tid] += red[tid + st]; __syncthreads(); }
  if (tid == 0) bag_ws[b] = has ? red[0] : 0.0f;
}

__global__ void loss_kernel(const float* __restrict__ bag_ws, const float* __restrict__ labels,
                            float* __restrict__ out) {
  if (threadIdx.x == 0 && blockIdx.x == 0) {
    float t = 0;
    for (int b = 0; b < BCH; ++b) {
      float x = bag_ws[b];
      float sp = fmaxf(x, 0.0f) + log1pf(expf(-fabsf(x)));
      t += sp - x * labels[b];
    }
    out[0] = t / (float)BCH;
  }
}

extern "C" void kernel_launch(void* const* d_in, const int* in_sizes, int n_in,
                              void* d_out, int out_size, void* d_ws, size_t ws_size,
                              hipStream_t stream) {
  (void)in_sizes; (void)n_in; (void)out_size; (void)ws_size;
  const float* state = (const float*)d_in[0];
  const float* trig  = (const float*)d_in[1];
  const float* gnn   = (const float*)d_in[2];
  const int*   zone  = (const int*)d_in[3];
  const int*   cats  = (const int*)d_in[4];
  const float* labels = (const float*)d_in[5];
  const float* s2t_qkv_w = (const float*)d_in[6];
  const float* s2t_qkv_b = (const float*)d_in[7];
  const float* s2t_out_w = (const float*)d_in[8];
  const float* s2t_out_b = (const float*)d_in[9];
  const float* t2s_qkv_w = (const float*)d_in[10];
  const float* t2s_qkv_b = (const float*)d_in[11];
  const float* t2s_out_w = (const float*)d_in[12];
  const float* t2s_out_b = (const float*)d_in[13];
  const float* fconv1_w = (const float*)d_in[14];
  const float* fbn1_g = (const float*)d_in[15];
  const float* fbn1_b = (const float*)d_in[16];
  const float* fconv2_w = (const float*)d_in[17];
  const float* fbn2_g = (const float*)d_in[18];
  const float* fbn2_b = (const float*)d_in[19];
  const float* outc_w = (const float*)d_in[20];
  const float* outc_b = (const float*)d_in[21];
  const float* attn1_w = (const float*)d_in[22];
  const float* attn1_b = (const float*)d_in[23];
  const float* attn2_w = (const float*)d_in[24];
  const float* attn2_b = (const float*)d_in[25];

  float* ws = (float*)d_ws;
  const size_t NBP = (size_t)BCH * L * 128; // 1,048,576
  size_t o = 0;
  float* c1 = ws + o; o += NBP;            // conv1 out, pixel-major f32
  float* c2 = ws + o; o += NBP;            // conv2 out, channel-major f32
  float* stats = ws + o; o += 512;
  float* score = ws + o; o += (size_t)BCH * L;
  float* plog = ws + o; o += (size_t)BCH * L;
  float* bag = ws + o; o += 8;
  short* Xs = (short*)(ws + o); o += NBP / 2;
  short* Xt = (short*)(ws + o); o += NBP / 2;
  short* qsb = (short*)(ws + o); o += NBP / 2;
  short* ksb = (short*)(ws + o); o += NBP / 2;   // head-packed K
  short* qtb = (short*)(ws + o); o += NBP / 2;
  short* ktb = (short*)(ws + o); o += NBP / 2;   // head-packed K
  short* vTsb = (short*)(ws + o); o += NBP / 2;
  short* vTtb = (short*)(ws + o); o += NBP / 2;
  short* aosb = (short*)(ws + o); o += NBP / 2;
  short* aotb = (short*)(ws + o); o += NBP / 2;
  short* fusedPM = (short*)(ws + o); o += (size_t)BCH * L * CPAD / 2;  // 1,179,648
  short* X2 = (short*)(ws + o); o += NBP / 2;
  short* W1b = (short*)(ws + o); o += (9 * 128 * CPAD) / 2;   // 165,888
  short* W2b = (short*)(ws + o); o += (9 * 128 * 128) / 2;    // 73,728
  short* wSb = (short*)(ws + o); o += 24576;
  short* wTb = (short*)(ws + o); o += 24576;
  short* woSb = (short*)(ws + o); o += 8192;
  short* woTb = (short*)(ws + o); o += 8192;

  prep_weights<<<192, 256, 0, stream>>>(s2t_qkv_w, t2s_qkv_w, s2t_out_w, t2s_out_w,
                                        wSb, wTb, woSb, woTb);
  prep_conv1<<<1296, 256, 0, stream>>>(fconv1_w, W1b);
  prep_conv2<<<576, 256, 0, stream>>>(fconv2_w, W2b);

  transpose_kernel<<<dim3(128, 4, BCH), 256, 0, stream>>>(state, Xs);
  transpose_kernel<<<dim3(128, 4, BCH), 256, 0, stream>>>(trig, Xt);

  gemm_qk<<<dim3(128, 4), 256, 0, stream>>>(Xs, Xt, wSb, wTb, s2t_qkv_b, t2s_qkv_b,
                                            qsb, ksb, qtb, ktb);
  gemm_v<<<dim3(128, 2), 256, 0, stream>>>(Xs, Xt, wSb, wTb, s2t_qkv_b, t2s_qkv_b,
                                           vTsb, vTtb);

  flash_attn_kernel<<<dim3(64, NHEAD, BCH), 256, 0, stream>>>(qsb, ksb, vTsb, aosb);
  flash_attn_kernel<<<dim3(64, NHEAD, BCH), 256, 0, stream>>>(qtb, ktb, vTtb, aotb);

  gemm_o<<<dim3(128, 2), 256, 0, stream>>>(aosb, aotb, woSb, woTb, s2t_out_b, t2s_out_b,
                                           fusedPM);
  copy_gnn_pm<<<1024, 256, 0, stream>>>(gnn, fusedPM);

  conv1_mfma<<<256, 128, 0, stream>>>(fusedPM, W1b, c1);
  bnstats_pm<<<128, 256, 0, stream>>>(c1, stats, stats + 128);
  bnapply_pm<<<4096, 256, 0, stream>>>(c1, stats, stats + 128, fbn1_g, fbn1_b, X2);

  conv2_mfma<<<256, 128, 0, stream>>>(X2, W2b, c2);
  bnstats_kernel<<<128, 256, 0, stream>>>(c2, stats + 256, stats + 384);
  bnapply_kernel<<<4096, 256, 0, stream>>>(c2, stats + 256, stats + 384, fbn2_g, fbn2_b);

  head_kernel<<<BCH * 64, 256, 0, stream>>>(c2, attn1_w, attn1_b, attn2_w, attn2_b,
                                            outc_w, outc_b, score, plog);

  finalize_kernel<<<BCH, 256, 0, stream>>>(score, plog, zone, cats, (float*)d_out + 1, bag);
  loss_kernel<<<1, 64, 0, stream>>>(bag, labels, (float*)d_out);
}

// Round 5
// 513.261 us; speedup vs baseline: 11.2739x; 1.0245x over previous
//
#include <hip/hip_runtime.h>
#include <hip/hip_bf16.h>
#include <math.h>

#define L 4096
#define ECH 128
#define BCH 2
#define NHEAD 4
#define FUSEDC 257
#define CPAD 288   // fused channels padded to multiple of 32 (16B-aligned rows)

typedef __attribute__((ext_vector_type(8))) short bs8;
typedef __attribute__((ext_vector_type(4))) short bs4;
typedef __attribute__((ext_vector_type(4))) float fx4;

// log2(e)/sqrt(32): QK^T scores land directly in exp2 domain
#define SCL 0.25503518f

// round-to-nearest-even f32 -> bf16 bits
static __device__ __forceinline__ short f2bfs(float x) {
  unsigned u = __float_as_uint(x);
  u += 0x7fffu + ((u >> 16) & 1u);
  return (short)(u >> 16);
}

static __device__ __forceinline__ float exp2a(float x) {
  float r; asm("v_exp_f32 %0, %1" : "=v"(r) : "v"(x)); return r;
}

static __device__ __forceinline__ unsigned pk2(float lo, float hi) {
  unsigned r; asm("v_cvt_pk_bf16_f32 %0, %1, %2" : "=v"(r) : "v"(lo), "v"(hi)); return r;
}

// ---------------- transpose (B,128,4096) f32 -> (B,4096,128) bf16, both inputs ----
__global__ void transpose_kernel(const float* __restrict__ sf, const float* __restrict__ tf,
                                 short* __restrict__ Xs, short* __restrict__ Xt) {
  __shared__ float t[32][33];
  int z = blockIdx.z; int b = z & 1; int sel = z >> 1;
  const float* in = sel ? tf : sf;
  short* out = sel ? Xt : Xs;
  int bx = blockIdx.x * 32;
  int by = blockIdx.y * 32;
  int tx = threadIdx.x & 31, ty = threadIdx.x >> 5;
  const float* ip = in + (size_t)b * ECH * L;
  short* op = out + (size_t)b * L * ECH;
#pragma unroll
  for (int r = ty; r < 32; r += 8)
    t[r][tx] = ip[(size_t)(by + r) * L + bx + tx];
  __syncthreads();
#pragma unroll
  for (int r = ty; r < 32; r += 8)
    op[(size_t)(bx + r) * ECH + by + tx] = f2bfs(t[tx][r]);
}

// ---------------- all weight prep in one kernel ----------------
// [0, 331776): conv1 -> [tap][co][ci_pad];  [331776, 479232): conv2 -> [tap][co][ci]
// [479232, 528384): attention qkv (Q rows pre-scaled by SCL) + out-proj
__global__ void prep_all(const float* __restrict__ c1w, const float* __restrict__ c2w,
                         const float* __restrict__ wS, const float* __restrict__ wT,
                         const float* __restrict__ woS, const float* __restrict__ woT,
                         short* __restrict__ W1b, short* __restrict__ W2b,
                         short* __restrict__ wSb, short* __restrict__ wTb,
                         short* __restrict__ woSb, short* __restrict__ woTb) {
  int i = blockIdx.x * 256 + threadIdx.x;
  if (i < 331776) {
    int ci = i % CPAD; int rest = i / CPAD; int co = rest & 127; int tap = rest >> 7;
    W1b[i] = (ci < FUSEDC) ? f2bfs(c1w[(co * FUSEDC + ci) * 9 + tap]) : (short)0;
  } else if (i < 479232) {
    int j = i - 331776;
    int ci = j & 127; int co = (j >> 7) & 127; int tap = j >> 14;
    W2b[j] = f2bfs(c2w[(co * 128 + ci) * 9 + tap]);
  } else {
    int k = i - 479232; // [0, 49152)
    float s = (k < 16384) ? SCL : 1.0f;
    wSb[k] = f2bfs(wS[k] * s);
    wTb[k] = f2bfs(wT[k] * s);
    if (k < 16384) {
      woSb[k] = f2bfs(woS[k]);
      woTb[k] = f2bfs(woT[k]);
    }
  }
}

// ---------------- merged QKV GEMM: 6 units ----------------
// units 0-3: Q/K (A=X,B=W^T; Q pixel-major, K head-packed); units 4-5: V (A=W,B=X^T -> V^T)
__global__ void __launch_bounds__(256)
gemm_qkv(const short* __restrict__ Xs, const short* __restrict__ Xt,
         const short* __restrict__ wSb, const short* __restrict__ wTb,
         const float* __restrict__ bS, const float* __restrict__ bT,
         short* __restrict__ qs, short* __restrict__ ks,
         short* __restrict__ qt, short* __restrict__ kt,
         short* __restrict__ vTs, short* __restrict__ vTt) {
  int unit = blockIdx.y;
  const short* X; const short* W; const float* bias; short* out; float scale; int mode;
  switch (unit) {
    case 0: X = Xs; W = wSb;         bias = bS;       out = qs;  scale = SCL; mode = 0; break;
    case 1: X = Xt; W = wSb + 16384; bias = bS + 128; out = ks;  scale = 1.f; mode = 1; break;
    case 2: X = Xt; W = wTb;         bias = bT;       out = qt;  scale = SCL; mode = 0; break;
    case 3: X = Xs; W = wTb + 16384; bias = bT + 128; out = kt;  scale = 1.f; mode = 1; break;
    case 4: X = Xt; W = wSb + 32768; bias = bS + 256; out = vTs; scale = 1.f; mode = 2; break;
    default:X = Xs; W = wTb + 32768; bias = bT + 256; out = vTt; scale = 1.f; mode = 2; break;
  }
  int tid = threadIdx.x;
  int wv = tid >> 6, lane = tid & 63, u = lane >> 4, r = lane & 15;
  int pblk = blockIdx.x * 64 + wv * 16;
  const short* xrow = X + (size_t)(pblk + r) * 128;
  fx4 acc[8] = {};
  if (mode != 2) {
#pragma unroll
    for (int ksx = 0; ksx < 4; ++ksx) {
      int k0 = ksx * 32 + u * 8;
      bs8 a = *(const bs8*)(xrow + k0);
      const short* wp = W + (size_t)r * 128 + k0;
#pragma unroll
      for (int t = 0; t < 8; ++t) {
        bs8 wf = *(const bs8*)(wp + (size_t)t * 16 * 128);
        acc[t] = __builtin_amdgcn_mfma_f32_16x16x32_bf16(a, wf, acc[t], 0, 0, 0);
      }
    }
  } else {
#pragma unroll
    for (int ksx = 0; ksx < 4; ++ksx) {
      int k0 = ksx * 32 + u * 8;
      bs8 xb = *(const bs8*)(xrow + k0);
      const short* wp = W + (size_t)r * 128 + k0;
#pragma unroll
      for (int t = 0; t < 8; ++t) {
        bs8 wf = *(const bs8*)(wp + (size_t)t * 16 * 128);
        acc[t] = __builtin_amdgcn_mfma_f32_16x16x32_bf16(wf, xb, acc[t], 0, 0, 0);
      }
    }
  }
  if (mode == 0) {
#pragma unroll
    for (int t = 0; t < 8; ++t) {
      float bv = bias[t * 16 + r] * scale;
#pragma unroll
      for (int reg = 0; reg < 4; ++reg) {
        int p = pblk + u * 4 + reg;
        out[(size_t)p * 128 + t * 16 + r] = f2bfs(acc[t][reg] + bv);
      }
    }
  } else if (mode == 1) {
#pragma unroll
    for (int t = 0; t < 8; ++t) {
      int och = t * 16 + r, h = och >> 5, d = och & 31;
      float bv = bias[och];
#pragma unroll
      for (int reg = 0; reg < 4; ++reg) {
        int p = pblk + u * 4 + reg;
        int b = p >> 12, pl = p & 4095;
        out[(((size_t)(b * NHEAD + h) * L + pl) << 5) + d] = f2bfs(acc[t][reg] + bv);
      }
    }
  } else {
    int p = pblk + r;
    int b = p >> 12, pl = p & 4095;
#pragma unroll
    for (int t = 0; t < 8; ++t) {
#pragma unroll
      for (int reg = 0; reg < 4; ++reg) {
        int och = t * 16 + u * 4 + reg;
        int h = och >> 5, d = och & 31;
        out[((size_t)(b * NHEAD + h) * 32 + d) * L + pl] = f2bfs(acc[t][reg] + bias[och]);
      }
    }
  }
}

// ---------------- out-projection -> fusedPM + gnn/pad channels ----------------
__global__ void __launch_bounds__(256)
gemm_o(const short* __restrict__ aosb, const short* __restrict__ aotb,
       const short* __restrict__ woSb, const short* __restrict__ woTb,
       const float* __restrict__ boS, const float* __restrict__ boT,
       const float* __restrict__ gnn, short* __restrict__ fusedPM) {
  int unit = blockIdx.y;
  const short* X = unit ? aotb : aosb;
  const short* W = unit ? woTb : woSb;
  const float* bias = unit ? boT : boS;
  int ochbase = unit ? 128 : 0;
  int tid = threadIdx.x;
  int wv = tid >> 6, lane = tid & 63, u = lane >> 4, r = lane & 15;
  int pblk = blockIdx.x * 64 + wv * 16;
  const short* xrow = X + (size_t)(pblk + r) * 128;
  fx4 acc[8] = {};
#pragma unroll
  for (int ksx = 0; ksx < 4; ++ksx) {
    int k0 = ksx * 32 + u * 8;
    bs8 a = *(const bs8*)(xrow + k0);
    const short* wp = W + (size_t)r * 128 + k0;
#pragma unroll
    for (int t = 0; t < 8; ++t) {
      bs8 wf = *(const bs8*)(wp + (size_t)t * 16 * 128);
      acc[t] = __builtin_amdgcn_mfma_f32_16x16x32_bf16(a, wf, acc[t], 0, 0, 0);
    }
  }
#pragma unroll
  for (int t = 0; t < 8; ++t) {
    float bv = bias[t * 16 + r];
#pragma unroll
    for (int reg = 0; reg < 4; ++reg) {
      int p = pblk + u * 4 + reg;
      fusedPM[(size_t)p * CPAD + ochbase + t * 16 + r] = f2bfs(acc[t][reg] + bv);
    }
  }
  if (unit == 0) {
    int base = blockIdx.x * 64;
    for (int t2 = tid; t2 < 64 * 32; t2 += 256) {
      int p = base + (t2 >> 5), j = t2 & 31;
      fusedPM[(size_t)p * CPAD + 256 + j] = (j == 0) ? f2bfs(gnn[p]) : (short)0;
    }
  }
}

// ---------------- merged bf16 MFMA flash attention, KVBLK=64, exp2 domain ---------
// grid (64, NHEAD, 2*BCH): z = att*2 + b. 4 waves/block, 16 q-rows/wave.
__global__ void __launch_bounds__(256)
flash_attn2(const short* __restrict__ Qs, const short* __restrict__ Ks,
            const short* __restrict__ Vs, short* __restrict__ Os,
            const short* __restrict__ Qt, const short* __restrict__ Kt,
            const short* __restrict__ Vt, short* __restrict__ Ot) {
  int z = blockIdx.z;
  int att = z >> 1, b = z & 1;
  const short* Q = att ? Qt : Qs;
  const short* K = att ? Kt : Ks;
  const short* VT = att ? Vt : Vs;
  short* O = att ? Ot : Os;
  int tid = threadIdx.x;
  int wid = tid >> 6, lane = tid & 63;
  int u = lane >> 4, r = lane & 15;
  int h = blockIdx.y;
  int qt = (blockIdx.x << 2) + wid;
  bs8 qf = *(const bs8*)(Q + ((size_t)(b * L + (qt << 4) + r) * 128 + h * 32 + u * 8));
  const short* Kb = K + (((size_t)(b * NHEAD + h) * L) << 5) + u * 8;
  const short* Vb = VT + ((size_t)(b * NHEAD + h) * 32) * (size_t)L;
  const short* v0p = Vb + (size_t)r * L + (u << 2);
  const short* v1p = Vb + (size_t)(16 + r) * L + (u << 2);
  fx4 o0 = {0.f, 0.f, 0.f, 0.f}, o1 = {0.f, 0.f, 0.f, 0.f};
  float m_run = -1.0e30f, l_run = 0.0f;
  for (int k0 = 0; k0 < L; k0 += 64) {
    bs8 a0 = *(const bs8*)(Kb + (((size_t)(k0 + r)) << 5));
    bs8 a1 = *(const bs8*)(Kb + (((size_t)(k0 + 16 + r)) << 5));
    bs8 a2 = *(const bs8*)(Kb + (((size_t)(k0 + 32 + r)) << 5));
    bs8 a3 = *(const bs8*)(Kb + (((size_t)(k0 + 48 + r)) << 5));
    fx4 zz = {0.f, 0.f, 0.f, 0.f};
    fx4 s0 = __builtin_amdgcn_mfma_f32_16x16x32_bf16(a0, qf, zz, 0, 0, 0);
    fx4 s1 = __builtin_amdgcn_mfma_f32_16x16x32_bf16(a1, qf, zz, 0, 0, 0);
    fx4 s2 = __builtin_amdgcn_mfma_f32_16x16x32_bf16(a2, qf, zz, 0, 0, 0);
    fx4 s3 = __builtin_amdgcn_mfma_f32_16x16x32_bf16(a3, qf, zz, 0, 0, 0);
    bs4 w0 = *(const bs4*)(v0p + k0);
    bs4 w1 = *(const bs4*)(v0p + k0 + 16);
    bs4 w2 = *(const bs4*)(v0p + k0 + 32);
    bs4 w3 = *(const bs4*)(v0p + k0 + 48);
    bs4 w4 = *(const bs4*)(v1p + k0);
    bs4 w5 = *(const bs4*)(v1p + k0 + 16);
    bs4 w6 = *(const bs4*)(v1p + k0 + 32);
    bs4 w7 = *(const bs4*)(v1p + k0 + 48);
    bs8 vb0lo = __builtin_shufflevector(w0, w1, 0, 1, 2, 3, 4, 5, 6, 7);
    bs8 vb0hi = __builtin_shufflevector(w2, w3, 0, 1, 2, 3, 4, 5, 6, 7);
    bs8 vb1lo = __builtin_shufflevector(w4, w5, 0, 1, 2, 3, 4, 5, 6, 7);
    bs8 vb1hi = __builtin_shufflevector(w6, w7, 0, 1, 2, 3, 4, 5, 6, 7);
    float mx = fmaxf(fmaxf(fmaxf(s0[0], s0[1]), fmaxf(s0[2], s0[3])),
                     fmaxf(fmaxf(s1[0], s1[1]), fmaxf(s1[2], s1[3])));
    mx = fmaxf(mx, fmaxf(fmaxf(fmaxf(s2[0], s2[1]), fmaxf(s2[2], s2[3])),
                         fmaxf(fmaxf(s3[0], s3[1]), fmaxf(s3[2], s3[3]))));
    mx = fmaxf(mx, __shfl_xor(mx, 16));
    mx = fmaxf(mx, __shfl_xor(mx, 32));
    float m_new = fmaxf(m_run, mx);
    float fsc = exp2a(m_run - m_new);
    fx4 p0, p1, p2, p3;
#pragma unroll
    for (int i = 0; i < 4; ++i) {
      p0[i] = exp2a(s0[i] - m_new);
      p1[i] = exp2a(s1[i] - m_new);
      p2[i] = exp2a(s2[i] - m_new);
      p3[i] = exp2a(s3[i] - m_new);
    }
    float ls = ((p0[0] + p0[1]) + (p0[2] + p0[3])) + ((p1[0] + p1[1]) + (p1[2] + p1[3]))
             + ((p2[0] + p2[1]) + (p2[2] + p2[3])) + ((p3[0] + p3[1]) + (p3[2] + p3[3]));
    ls += __shfl_xor(ls, 16);
    ls += __shfl_xor(ls, 32);
    l_run = l_run * fsc + ls;
    m_run = m_new;
#pragma unroll
    for (int reg = 0; reg < 4; ++reg) {
      float fo = __shfl(fsc, (u << 2) + reg);
      o0[reg] *= fo; o1[reg] *= fo;
    }
    union { unsigned w32[4]; bs8 v; } plo, phi;
    plo.w32[0] = pk2(p0[0], p0[1]); plo.w32[1] = pk2(p0[2], p0[3]);
    plo.w32[2] = pk2(p1[0], p1[1]); plo.w32[3] = pk2(p1[2], p1[3]);
    phi.w32[0] = pk2(p2[0], p2[1]); phi.w32[1] = pk2(p2[2], p2[3]);
    phi.w32[2] = pk2(p3[0], p3[1]); phi.w32[3] = pk2(p3[2], p3[3]);
    o0 = __builtin_amdgcn_mfma_f32_16x16x32_bf16(plo.v, vb0lo, o0, 0, 0, 0);
    o0 = __builtin_amdgcn_mfma_f32_16x16x32_bf16(phi.v, vb0hi, o0, 0, 0, 0);
    o1 = __builtin_amdgcn_mfma_f32_16x16x32_bf16(plo.v, vb1lo, o1, 0, 0, 0);
    o1 = __builtin_amdgcn_mfma_f32_16x16x32_bf16(phi.v, vb1hi, o1, 0, 0, 0);
  }
#pragma unroll
  for (int reg = 0; reg < 4; ++reg) {
    float linv = 1.0f / __shfl(l_run, (u << 2) + reg);
    size_t ob = ((size_t)b * L + (qt << 4) + (u << 2) + reg) * 128 + h * 32;
    O[ob + r] = f2bfs(o0[reg] * linv);
    O[ob + 16 + r] = f2bfs(o1[reg] * linv);
  }
}

// ---------------- conv1 3x3 via MFMA: fusedPM (8192xCPAD bf16) -> c1 pm f32 -------
__global__ void __launch_bounds__(128)
conv1_mfma(const short* __restrict__ X, const short* __restrict__ W,
           float* __restrict__ out) {
  int tid = threadIdx.x;
  int wv = tid >> 6, lane = tid & 63, u = lane >> 4, r = lane & 15;
  int pblk = blockIdx.x * 32 + wv * 16;
  int b = pblk >> 12, y = (pblk & 4095) >> 6, x0 = pblk & 63;
  fx4 acc[8] = {};
  for (int tap = 0; tap < 9; ++tap) {
    int dy = tap / 3 - 1, dx = tap % 3 - 1;
    int yy = y + dy;
    if (yy < 0 || yy > 63) { __syncthreads(); continue; }
    int xx = x0 + r + dx;
    bool valid = (xx >= 0) && (xx <= 63);
    const short* xrow = X + (size_t)((b << 12) + (yy << 6) + x0 + dx + r) * CPAD;
    const short* wtap = W + ((size_t)tap * 128 + r) * CPAD;
#pragma unroll
    for (int kc = 0; kc < 9; ++kc) {
      int k0 = kc * 32 + u * 8;
      bs8 a = {};
      if (valid) a = *(const bs8*)(xrow + k0);
#pragma unroll
      for (int t = 0; t < 8; ++t) {
        bs8 wf = *(const bs8*)(wtap + (size_t)t * 16 * CPAD + k0);
        acc[t] = __builtin_amdgcn_mfma_f32_16x16x32_bf16(a, wf, acc[t], 0, 0, 0);
      }
    }
    __syncthreads();
  }
#pragma unroll
  for (int t = 0; t < 8; ++t)
#pragma unroll
    for (int reg = 0; reg < 4; ++reg)
      out[(size_t)(pblk + u * 4 + reg) * 128 + t * 16 + r] = acc[t][reg];
}

// ---------------- conv2 3x3 via MFMA: X2 (8192x128 bf16 pm) -> c2 channel-major ---
__global__ void __launch_bounds__(128)
conv2_mfma(const short* __restrict__ X, const short* __restrict__ W,
           float* __restrict__ out) {
  int tid = threadIdx.x;
  int wv = tid >> 6, lane = tid & 63, u = lane >> 4, r = lane & 15;
  int pblk = blockIdx.x * 32 + wv * 16;
  int b = pblk >> 12, y = (pblk & 4095) >> 6, x0 = pblk & 63;
  fx4 acc[8] = {};
  for (int tap = 0; tap < 9; ++tap) {
    int dy = tap / 3 - 1, dx = tap % 3 - 1;
    int yy = y + dy;
    if (yy < 0 || yy > 63) { __syncthreads(); continue; }
    int xx = x0 + r + dx;
    bool valid = (xx >= 0) && (xx <= 63);
    const short* xrow = X + (size_t)((b << 12) + (yy << 6) + x0 + dx + r) * 128;
    const short* wtap = W + ((size_t)tap * 128 + r) * 128;
#pragma unroll
    for (int kc = 0; kc < 4; ++kc) {
      int k0 = kc * 32 + u * 8;
      bs8 xb = {};
      if (valid) xb = *(const bs8*)(xrow + k0);
#pragma unroll
      for (int t = 0; t < 8; ++t) {
        bs8 wf = *(const bs8*)(wtap + (size_t)t * 16 * 128 + k0);
        acc[t] = __builtin_amdgcn_mfma_f32_16x16x32_bf16(wf, xb, acc[t], 0, 0, 0);
      }
    }
    __syncthreads();
  }
  int px = y * 64 + x0 + r;
#pragma unroll
  for (int t = 0; t < 8; ++t)
#pragma unroll
    for (int reg = 0; reg < 4; ++reg) {
      int och = t * 16 + u * 4 + reg;
      out[((size_t)(b * 128 + och) << 12) + px] = acc[t][reg];
    }
}

// ---------------- BN stats over pixel-major f32 ----------------
__global__ void bnstats_pm(const float* __restrict__ x, float* __restrict__ mean,
                           float* __restrict__ rstd) {
  __shared__ float rs[256], rq[256];
  int c = blockIdx.x, tid = threadIdx.x;
  float s = 0, q = 0;
  for (int p = tid; p < BCH * L; p += 256) {
    float v = x[(size_t)p * 128 + c];
    s += v; q += v * v;
  }
  rs[tid] = s; rq[tid] = q; __syncthreads();
  for (int st = 128; st > 0; st >>= 1) { if (tid < st) { rs[tid] += rs[tid + st]; rq[tid] += rq[tid + st]; } __syncthreads(); }
  if (tid == 0) {
    float m = rs[0] / (float)(BCH * L);
    float v = rq[0] / (float)(BCH * L) - m * m;
    mean[c] = m;
    rstd[c] = rsqrtf(v + 1e-5f);
  }
}

__global__ void bnapply_pm(const float* __restrict__ x, const float* __restrict__ mean,
                           const float* __restrict__ rstd, const float* __restrict__ g,
                           const float* __restrict__ bb, short* __restrict__ out) {
  int i = blockIdx.x * 256 + threadIdx.x;
  int c = i & 127;
  float v = x[i];
  out[i] = f2bfs(fmaxf(g[c] * (v - mean[c]) * rstd[c] + bb[c], 0.0f));
}

// ---------------- BN stats / apply, channel-major (for c2) ----------------
__global__ void bnstats_kernel(const float* __restrict__ x, float* __restrict__ mean, float* __restrict__ rstd) {
  __shared__ float rs[256], rq[256];
  int c = blockIdx.x, tid = threadIdx.x;
  float s = 0, q = 0;
  for (int i = tid; i < BCH * L; i += 256) {
    int b = i >> 12, p = i & 4095;
    float v = x[((size_t)(b * 128 + c)) * L + p];
    s += v; q += v * v;
  }
  rs[tid] = s; rq[tid] = q; __syncthreads();
  for (int st = 128; st > 0; st >>= 1) { if (tid < st) { rs[tid] += rs[tid + st]; rq[tid] += rq[tid + st]; } __syncthreads(); }
  if (tid == 0) {
    float m = rs[0] / (float)(BCH * L);
    float v = rq[0] / (float)(BCH * L) - m * m;
    mean[c] = m;
    rstd[c] = rsqrtf(v + 1e-5f);
  }
}

__global__ void bnapply_kernel(float* __restrict__ x, const float* __restrict__ mean, const float* __restrict__ rstd,
                               const float* __restrict__ g, const float* __restrict__ bb) {
  int i = blockIdx.x * 256 + threadIdx.x;
  int c = (i >> 12) & 127;
  float v = x[i];
  float y = g[c] * (v - mean[c]) * rstd[c] + bb[c];
  x[i] = fmaxf(y, 0.0f);
}

// ---------------- fused 1x1 heads ----------------
__global__ void head_kernel(const float* __restrict__ feat,
                            const float* __restrict__ w1, const float* __restrict__ b1,
                            const float* __restrict__ w2, const float* __restrict__ b2,
                            const float* __restrict__ wo, const float* __restrict__ bo,
                            float* __restrict__ score, float* __restrict__ plog) {
  __shared__ float f[128][64];
  __shared__ float r1[4][64], r2[4][64];
  int by = blockIdx.x; int b = by >> 6, y = by & 63;
  int tid = threadIdx.x;
  int x = tid & 63, g4 = tid >> 6;
  for (int c = g4; c < 128; c += 4)
    f[c][x] = feat[((size_t)(b * 128 + c)) * L + y * 64 + x];
  __syncthreads();
  int cb = g4 * 32;
  float a[32];
#pragma unroll
  for (int i = 0; i < 32; ++i) a[i] = b1[cb + i];
  for (int ci = 0; ci < 128; ++ci) {
    float fv = f[ci][x];
#pragma unroll
    for (int i = 0; i < 32; ++i) a[i] += w1[(size_t)(cb + i) * 128 + ci] * fv;
  }
  float sp = 0.0f;
#pragma unroll
  for (int i = 0; i < 32; ++i) sp += w2[cb + i] * fmaxf(a[i], 0.0f);
  float plp = 0.0f;
#pragma unroll
  for (int i = 0; i < 32; ++i) plp += wo[cb + i] * f[cb + i][x];
  r1[g4][x] = sp; r2[g4][x] = plp;
  __syncthreads();
  if (tid < 64) {
    int xx = tid;
    float s = r1[0][xx] + r1[1][xx] + r1[2][xx] + r1[3][xx] + b2[0];
    float pl = r2[0][xx] + r2[1][xx] + r2[2][xx] + r2[3][xx] + bo[0];
    score[(size_t)b * L + y * 64 + xx] = s;
    plog[(size_t)b * L + y * 64 + xx] = pl;
  }
}

// ---------------- masked softmax + attention maps + bag ----------------
__global__ void finalize_kernel(const float* __restrict__ score, const float* __restrict__ plog,
                                const int* __restrict__ zone, const int* __restrict__ cats,
                                float* __restrict__ maps, float* __restrict__ bag_ws) {
  __shared__ float sc[4096];
  __shared__ float red[256];
  __shared__ int ired[256];
  int b = blockIdx.x, tid = threadIdx.x;
  int cat = cats[b];
  float lmax = -3e38f; int lhas = 0;
  for (int p = tid; p < 4096; p += 256) {
    int z = zone[(size_t)b * 4096 + p];
    int m = (z == cat) && (z > 0);
    float s = m ? score[(size_t)b * 4096 + p] : -1e9f;
    sc[p] = s; lmax = fmaxf(lmax, s); lhas |= m;
  }
  red[tid] = lmax; ired[tid] = lhas; __syncthreads();
  for (int st = 128; st > 0; st >>= 1) {
    if (tid < st) { red[tid] = fmaxf(red[tid], red[tid + st]); ired[tid] |= ired[tid + st]; }
    __syncthreads();
  }
  float gmax = red[0]; int has = ired[0];
  __syncthreads();
  float lsum = 0;
  for (int p = tid; p < 4096; p += 256) {
    float e = __expf(sc[p] - gmax);
    sc[p] = e; lsum += e;
  }
  red[tid] = lsum; __syncthreads();
  for (int st = 128; st > 0; st >>= 1) { if (tid < st) red[tid] += red[tid + st]; __syncthreads(); }
  float inv = 1.0f / red[0];
  __syncthreads();
  float lbag = 0;
  for (int p = tid; p < 4096; p += 256) {
    float w = sc[p] * inv;
    maps[(size_t)b * 4096 + p] = has ? w : 0.0f;
    int z = zone[(size_t)b * 4096 + p];
    if ((z == cat) && (z > 0)) lbag += plog[(size_t)b * 4096 + p] * w;
  }
  red[tid] = lbag; __syncthreads();
  for (int st = 128; st > 0; st >>= 1) { if (tid < st) red[tid] += red[tid + st]; __syncthreads(); }
  if (tid == 0) bag_ws[b] = has ? red[0] : 0.0f;
}

__global__ void loss_kernel(const float* __restrict__ bag_ws, const float* __restrict__ labels,
                            float* __restrict__ out) {
  if (threadIdx.x == 0 && blockIdx.x == 0) {
    float t = 0;
    for (int b = 0; b < BCH; ++b) {
      float x = bag_ws[b];
      float sp = fmaxf(x, 0.0f) + log1pf(expf(-fabsf(x)));
      t += sp - x * labels[b];
    }
    out[0] = t / (float)BCH;
  }
}

extern "C" void kernel_launch(void* const* d_in, const int* in_sizes, int n_in,
                              void* d_out, int out_size, void* d_ws, size_t ws_size,
                              hipStream_t stream) {
  (void)in_sizes; (void)n_in; (void)out_size; (void)ws_size;
  const float* state = (const float*)d_in[0];
  const float* trig  = (const float*)d_in[1];
  const float* gnn   = (const float*)d_in[2];
  const int*   zone  = (const int*)d_in[3];
  const int*   cats  = (const int*)d_in[4];
  const float* labels = (const float*)d_in[5];
  const float* s2t_qkv_w = (const float*)d_in[6];
  const float* s2t_qkv_b = (const float*)d_in[7];
  const float* s2t_out_w = (const float*)d_in[8];
  const float* s2t_out_b = (const float*)d_in[9];
  const float* t2s_qkv_w = (const float*)d_in[10];
  const float* t2s_qkv_b = (const float*)d_in[11];
  const float* t2s_out_w = (const float*)d_in[12];
  const float* t2s_out_b = (const float*)d_in[13];
  const float* fconv1_w = (const float*)d_in[14];
  const float* fbn1_g = (const float*)d_in[15];
  const float* fbn1_b = (const float*)d_in[16];
  const float* fconv2_w = (const float*)d_in[17];
  const float* fbn2_g = (const float*)d_in[18];
  const float* fbn2_b = (const float*)d_in[19];
  const float* outc_w = (const float*)d_in[20];
  const float* outc_b = (const float*)d_in[21];
  const float* attn1_w = (const float*)d_in[22];
  const float* attn1_b = (const float*)d_in[23];
  const float* attn2_w = (const float*)d_in[24];
  const float* attn2_b = (const float*)d_in[25];

  float* ws = (float*)d_ws;
  const size_t NBP = (size_t)BCH * L * 128; // 1,048,576
  size_t o = 0;
  float* c1 = ws + o; o += NBP;            // conv1 out, pixel-major f32
  float* c2 = ws + o; o += NBP;            // conv2 out, channel-major f32
  float* stats = ws + o; o += 512;
  float* score = ws + o; o += (size_t)BCH * L;
  float* plog = ws + o; o += (size_t)BCH * L;
  float* bag = ws + o; o += 8;
  short* Xs = (short*)(ws + o); o += NBP / 2;
  short* Xt = (short*)(ws + o); o += NBP / 2;
  short* qsb = (short*)(ws + o); o += NBP / 2;
  short* ksb = (short*)(ws + o); o += NBP / 2;   // head-packed K
  short* qtb = (short*)(ws + o); o += NBP / 2;
  short* ktb = (short*)(ws + o); o += NBP / 2;   // head-packed K
  short* vTsb = (short*)(ws + o); o += NBP / 2;
  short* vTtb = (short*)(ws + o); o += NBP / 2;
  short* aosb = (short*)(ws + o); o += NBP / 2;
  short* aotb = (short*)(ws + o); o += NBP / 2;
  short* fusedPM = (short*)(ws + o); o += (size_t)BCH * L * CPAD / 2;
  short* X2 = (short*)(ws + o); o += NBP / 2;
  short* W1b = (short*)(ws + o); o += (9 * 128 * CPAD) / 2;
  short* W2b = (short*)(ws + o); o += (9 * 128 * 128) / 2;
  short* wSb = (short*)(ws + o); o += 24576;
  short* wTb = (short*)(ws + o); o += 24576;
  short* woSb = (short*)(ws + o); o += 8192;
  short* woTb = (short*)(ws + o); o += 8192;

  prep_all<<<2064, 256, 0, stream>>>(fconv1_w, fconv2_w, s2t_qkv_w, t2s_qkv_w,
                                     s2t_out_w, t2s_out_w,
                                     W1b, W2b, wSb, wTb, woSb, woTb);
  transpose_kernel<<<dim3(128, 4, 2 * BCH), 256, 0, stream>>>(state, trig, Xs, Xt);

  gemm_qkv<<<dim3(128, 6), 256, 0, stream>>>(Xs, Xt, wSb, wTb, s2t_qkv_b, t2s_qkv_b,
                                             qsb, ksb, qtb, ktb, vTsb, vTtb);

  flash_attn2<<<dim3(64, NHEAD, 2 * BCH), 256, 0, stream>>>(qsb, ksb, vTsb, aosb,
                                                            qtb, ktb, vTtb, aotb);

  gemm_o<<<dim3(128, 2), 256, 0, stream>>>(aosb, aotb, woSb, woTb, s2t_out_b, t2s_out_b,
                                           gnn, fusedPM);

  conv1_mfma<<<256, 128, 0, stream>>>(fusedPM, W1b, c1);
  bnstats_pm<<<128, 256, 0, stream>>>(c1, stats, stats + 128);
  bnapply_pm<<<4096, 256, 0, stream>>>(c1, stats, stats + 128, fbn1_g, fbn1_b, X2);

  conv2_mfma<<<256, 128, 0, stream>>>(X2, W2b, c2);
  bnstats_kernel<<<128, 256, 0, stream>>>(c2, stats + 256, stats + 384);
  bnapply_kernel<<<4096, 256, 0, stream>>>(c2, stats + 256, stats + 384, fbn2_g, fbn2_b);

  head_kernel<<<BCH * 64, 256, 0, stream>>>(c2, attn1_w, attn1_b, attn2_w, attn2_b,
                                            outc_w, outc_b, score, plog);

  finalize_kernel<<<BCH, 256, 0, stream>>>(score, plog, zone, cats, (float*)d_out + 1, bag);
  loss_kernel<<<1, 64, 0, stream>>>(bag, labels, (float*)d_out);
}